// Round 2
// baseline (398.762 us; speedup 1.0000x reference)
//
#include <hip/hip_runtime.h>

// Problem constants
constexpr int B  = 8;
constexpr int C  = 256;
constexpr int Hh = 64;
constexpr int Ww = 64;
constexpr int P  = Hh * Ww;        // 4096 pixels
constexpr int CP = C * P;          // elements per (b,t) slice
constexpr int CT = 3 * C;          // 768 concat channels
constexpr int J  = B * P;          // 32768 columns

// NOTE: d_ws is never touched (ws writes correlated with container crashes
// rounds 1-3). Scratch lives in out[0 .. ~300K floats) = batch-0 slot-0,
// which k_copy overwrites LAST.

typedef __attribute__((ext_vector_type(8))) short short8;
typedef __attribute__((ext_vector_type(4))) float f32x4;

__device__ inline unsigned short bf16_rne(float f) {
    unsigned u = __float_as_uint(f);
    return (unsigned short)((u + 0x7fffu + ((u >> 16) & 1u)) >> 16);
}
__device__ inline unsigned pack2(float a, float b) {
    return (unsigned)bf16_rne(a) | ((unsigned)bf16_rne(b) << 16);
}

// ---------------------------------------------------------------------------
// Kernel: convert conv weights fp32 -> bf16 (RNE), layout unchanged [m][k]
// ---------------------------------------------------------------------------
__global__ __launch_bounds__(256) void k_wcvt(const float* __restrict__ Wg,
                                              unsigned short* __restrict__ Wb) {
    int i = blockIdx.x * 256 + threadIdx.x;   // 196608 elems, grid exact
    Wb[i] = bf16_rne(Wg[i]);
}

// ---------------------------------------------------------------------------
// Kernel: inv L2 norm of every prev/next feature vector (fp64 accumulate).
// Channel split across WAVES (not lanes): wave w of 4 handles channels
// [64w,64w+64) for a 64-pixel strip. Each wave-load = 64 consecutive
// pixels (fully coalesced, same pattern as the 89us baseline); 4096 waves
// total (4/SIMD) for latency hiding. LDS reduce across the 4 waves.
// (Round-0 lane-split broke coalescing: FETCH 64.7->114MB, dur 89->149us.)
// ---------------------------------------------------------------------------
__global__ __launch_bounds__(256) void k_norm(const float* __restrict__ x,
                                              float* __restrict__ invall) {
    __shared__ double red[4][64];
    const int t = threadIdx.x;
    const int w = t >> 6;                     // channel chunk (= wave id)
    const int l = t & 63;                     // pixel within strip
    const int gid = blockIdx.x * 64 + l;      // 0 .. 2J-1 (64 | 32768 -> side,b uniform)
    const int side = gid >> 15;
    const int j    = gid & (J - 1);
    const int b = j >> 12, p = j & (P - 1);
    const float* src = x + (size_t)(b * 3 + side) * CP + (size_t)w * 64 * P + p;
    double acc = 0.0;
    #pragma unroll 8
    for (int c = 0; c < 64; ++c) {
        float v = src[(size_t)c * P];
        acc = fma((double)v, (double)v, acc);
    }
    red[w][l] = acc;
    __syncthreads();
    if (t < 64) {
        double tot = red[0][t] + red[1][t] + red[2][t] + red[3][t];
        invall[side * J + (j & ~63) + t] =
            1.0f / fmaxf((float)sqrt(tot), 1e-12f);
    }
}

// ---------------------------------------------------------------------------
// Kernel: argmin cosine sim over 9 clipped neighbors (fp64 dots; common
// positive 1/|cur| dropped -> same ordering; strict < = first-min tie-break).
// Channel split across WAVES: wave w dots channels [64w,64w+64) for all 9
// neighbors of its 64-pixel strip (coalesced 64-px wave loads preserved).
// 18KB LDS holds the 4x9x64 fp64 partials; wave 0 sums chunks (duplicate
// clipped neighbors stay bit-identical -> tie-break unchanged) and argmins.
// Writes selected pixel index and its inv norm.
// ---------------------------------------------------------------------------
__global__ __launch_bounds__(256) void k_argmin(const float* __restrict__ x,
                                                const float* __restrict__ invall,
                                                int* __restrict__ sel,
                                                float* __restrict__ siv) {
    __shared__ double red[4][9][64];          // 18 KB
    const int t = threadIdx.x;
    const int w = t >> 6;                     // channel chunk (= wave id)
    const int l = t & 63;                     // pixel within strip
    const int j = blockIdx.x * 64 + l;        // 64 | 4096 -> b uniform per block
    const int side = blockIdx.y;
    const int b = j >> 12, p = j & (P - 1);
    const int y = p >> 6, xc = p & 63;

    int nidx[9];
    #pragma unroll
    for (int k = 0; k < 9; ++k) {
        int dy = k / 3 - 1, dx = k % 3 - 1;     // y_off=repeat, x_off=tile
        int yy = min(max(y + dy, 0), Hh - 1);
        int xx = min(max(xc + dx, 0), Ww - 1);
        nidx[k] = yy * Ww + xx;
    }

    const float* curp = x + (size_t)(b * 3 + 2) * CP + (size_t)w * 64 * P + p;
    const float* yb   = x + (size_t)(b * 3 + side) * CP + (size_t)w * 64 * P;

    double acc[9] = {0,0,0,0,0,0,0,0,0};
    #pragma unroll 2
    for (int c = 0; c < 64; ++c) {
        size_t co = (size_t)c * P;
        double xd = (double)curp[co];
        #pragma unroll
        for (int k = 0; k < 9; ++k)
            acc[k] = fma(xd, (double)yb[co + nidx[k]], acc[k]);
    }

    #pragma unroll
    for (int k = 0; k < 9; ++k) red[w][k][l] = acc[k];
    __syncthreads();

    if (t < 64) {
        const float* iv = invall + side * J + b * P;
        double best = (red[0][0][t] + red[1][0][t] + red[2][0][t] + red[3][0][t])
                      * (double)iv[nidx[0]];
        int bi = 0;
        #pragma unroll
        for (int k = 1; k < 9; ++k) {
            double s = (red[0][k][t] + red[1][k][t] + red[2][k][t] + red[3][k][t])
                       * (double)iv[nidx[k]];
            if (s < best) { best = s; bi = k; }
        }
        sel[side * J + j] = nidx[bi];
        siv[side * J + j] = iv[nidx[bi]];
    }
}

// ---------------------------------------------------------------------------
// Kernel: bf16 MFMA GEMM with fused gather+normalize+cvt of the feature
// matrix. C[m=256][j-tile of 128] = sum_k W[m][k] * F(k,j), K = 768.
// Grid: 256 blocks (J/128), 512 threads (8 waves; wave = 64m x 64n subtile;
// 4x4 frags of mfma_f32_16x16x32_bf16).
// LDS tiles store k-octets: As[ko][m][8], Bs[ko][n][8] -> frag loads are
// single ds_read_b128 (layouts per measured m89/m91 mappings).
// Raw conv output -> out slot 2.
// ---------------------------------------------------------------------------
__global__ __launch_bounds__(512) void k_gemm(const float* __restrict__ x,
                                              const unsigned short* __restrict__ Wb,
                                              const int* __restrict__ sel,
                                              const float* __restrict__ siv,
                                              float* __restrict__ out) {
    __shared__ unsigned short As[4][256][8];   // 16 KB, k-octet blocked
    __shared__ unsigned short Bs[4][128][8];   // 8 KB
    __shared__ int   sel_s[2][128];
    __shared__ float siv_s[2][128];

    const int t  = threadIdx.x;
    const int j0 = blockIdx.x * 128;
    const int b  = j0 >> 12, p0 = j0 & (P - 1);   // 128 | 4096 -> b uniform

    if (t < 256) {
        int side = t >> 7, jj = t & 127;
        sel_s[side][jj] = sel[side * J + j0 + jj];
        siv_s[side][jj] = siv[side * J + j0 + jj];
    }
    __syncthreads();

    const float* prevb = x + (size_t)(b * 3 + 0) * CP;
    const float* nextb = x + (size_t)(b * 3 + 1) * CP;
    const float* curb  = x + (size_t)(b * 3 + 2) * CP;

    const int lane = t & 63, w = t >> 6;
    const int q = lane >> 4, l16 = lane & 15;
    const int m0w = (w & 3) * 64;      // 4 m-quadrants of 256
    const int n0w = (w >> 2) * 64;     // 2 n-halves of 128

    const int jj = t & 127, kq = (t >> 7) & 3;   // B staging role
    const int ma = t & 255, kh = t >> 8;         // A staging role

    f32x4 acc[4][4];
    #pragma unroll
    for (int f = 0; f < 4; ++f)
        #pragma unroll
        for (int g = 0; g < 4; ++g)
            acc[f][g] = (f32x4){0.f, 0.f, 0.f, 0.f};

    for (int kk = 0; kk < CT; kk += 32) {
        // --- global loads into regs (no LDS yet) ---
        const unsigned short* wsrc = Wb + (size_t)ma * CT + kk + kh * 16;
        short8 wa0 = *(const short8*)wsrc;
        short8 wa1 = *(const short8*)(wsrc + 8);

        const float* src; float scale;
        int k0 = kq * 8;
        if (kk < 256) {
            src = prevb + (size_t)(kk + k0) * P + sel_s[0][jj];
            scale = siv_s[0][jj];
        } else if (kk < 512) {
            src = nextb + (size_t)(kk - 256 + k0) * P + sel_s[1][jj];
            scale = siv_s[1][jj];
        } else {
            src = curb + (size_t)(kk - 512 + k0) * P + p0 + jj;
            scale = 1.0f;
        }
        float f0 = src[0] * scale,             f1 = src[(size_t)P] * scale;
        float f2 = src[(size_t)2 * P] * scale, f3 = src[(size_t)3 * P] * scale;
        float f4 = src[(size_t)4 * P] * scale, f5 = src[(size_t)5 * P] * scale;
        float f6 = src[(size_t)6 * P] * scale, f7 = src[(size_t)7 * P] * scale;

        __syncthreads();   // prior iteration done reading LDS

        *(short8*)&As[kh * 2    ][ma][0] = wa0;
        *(short8*)&As[kh * 2 + 1][ma][0] = wa1;
        uint4 pk = make_uint4(pack2(f0, f1), pack2(f2, f3),
                              pack2(f4, f5), pack2(f6, f7));
        *(uint4*)&Bs[kq][jj][0] = pk;

        __syncthreads();

        short8 af[4], bfr[4];
        #pragma unroll
        for (int f = 0; f < 4; ++f)
            af[f] = *(const short8*)&As[q][m0w + f * 16 + l16][0];
        #pragma unroll
        for (int g = 0; g < 4; ++g)
            bfr[g] = *(const short8*)&Bs[q][n0w + g * 16 + l16][0];
        #pragma unroll
        for (int f = 0; f < 4; ++f)
            #pragma unroll
            for (int g = 0; g < 4; ++g)
                acc[f][g] = __builtin_amdgcn_mfma_f32_16x16x32_bf16(
                    af[f], bfr[g], acc[f][g], 0, 0, 0);
    }

    // epilogue: D[row=q*4+r][col=l16] per 16x16 frag (measured C/D layout)
    float* outb = out + (size_t)(b * 3 + 2) * CP;
    #pragma unroll
    for (int f = 0; f < 4; ++f)
        #pragma unroll
        for (int g = 0; g < 4; ++g)
            #pragma unroll
            for (int r = 0; r < 4; ++r) {
                int ch  = m0w + f * 16 + q * 4 + r;
                int col = p0 + n0w + g * 16 + l16;
                outb[(size_t)ch * P + col] = acc[f][g][r];
            }
}

// ---------------------------------------------------------------------------
// Kernel: per-channel BN stats + normalize + ReLU in place on out slot 2
// (one block per channel; block-local fp64 reduction; proven round 4)
// ---------------------------------------------------------------------------
__global__ __launch_bounds__(256) void k_bn(float* __restrict__ out,
                                            const float* __restrict__ gamma,
                                            const float* __restrict__ beta) {
    __shared__ double rs[256], rq[256];
    __shared__ float sc_s, sh_s;
    const int o = blockIdx.x, t = threadIdx.x;

    double s = 0.0, q = 0.0;
    for (int b = 0; b < B; ++b) {
        const float4* base =
            (const float4*)(out + (size_t)(b * 3 + 2) * CP + (size_t)o * P);
        #pragma unroll
        for (int i = 0; i < 4; ++i) {
            float4 v = base[i * 256 + t];
            s += (double)v.x + (double)v.y + (double)v.z + (double)v.w;
            q += (double)v.x * v.x + (double)v.y * v.y
               + (double)v.z * v.z + (double)v.w * v.w;
        }
    }
    rs[t] = s; rq[t] = q;
    __syncthreads();
    for (int off = 128; off > 0; off >>= 1) {
        if (t < off) { rs[t] += rs[t + off]; rq[t] += rq[t + off]; }
        __syncthreads();
    }
    if (t == 0) {
        double mean = rs[0] * (1.0 / (double)J);
        double var  = rq[0] * (1.0 / (double)J) - mean * mean;
        double inv  = 1.0 / sqrt(var + 1e-5);
        double sc   = (double)gamma[o] * inv;
        sc_s = (float)sc;
        sh_s = (float)((double)beta[o] - mean * sc);
    }
    __syncthreads();
    const float sc = sc_s, sh = sh_s;

    for (int b = 0; b < B; ++b) {
        float4* base =
            (float4*)(out + (size_t)(b * 3 + 2) * CP + (size_t)o * P);
        #pragma unroll
        for (int i = 0; i < 4; ++i) {
            float4 v = base[i * 256 + t];
            v.x = fmaxf(fmaf(v.x, sc, sh), 0.f);
            v.y = fmaxf(fmaf(v.y, sc, sh), 0.f);
            v.z = fmaxf(fmaf(v.z, sc, sh), 0.f);
            v.w = fmaxf(fmaf(v.w, sc, sh), 0.f);
            base[i * 256 + t] = v;
        }
    }
}

// ---------------------------------------------------------------------------
// Kernel: copy prev/next slices to output slots 0/1 (runs LAST: overwrites
// the scratch region used by earlier kernels)
// ---------------------------------------------------------------------------
__global__ __launch_bounds__(256) void k_copy(const float4* __restrict__ x4,
                                              float4* __restrict__ o4) {
    int tid = blockIdx.x * blockDim.x + threadIdx.x;
    const int per_b = 2 * CP / 4;
    const int bstr  = 3 * CP / 4;
    if (tid < B * per_b) {
        int b = tid / per_b;
        int r = tid - b * per_b;
        o4[b * bstr + r] = x4[b * bstr + r];
    }
}

// ---------------------------------------------------------------------------
extern "C" void kernel_launch(void* const* d_in, const int* in_sizes, int n_in,
                              void* d_out, int out_size, void* d_ws, size_t ws_size,
                              hipStream_t stream) {
    const float* x     = (const float*)d_in[0];
    const float* wconv = (const float*)d_in[1];
    const float* gamma = (const float*)d_in[2];
    const float* beta  = (const float*)d_in[3];
    float* out = (float*)d_out;
    (void)d_ws; (void)ws_size;   // deliberately unused

    // scratch inside out batch-0 slot-0 (first CP floats), overwritten by
    // k_copy at the end:
    float*          invall = out;                                 // 2*J f
    int*            sel    = (int*)(out + 2 * J);                 // 2*J i
    float*          siv    = out + 4 * J;                         // 2*J f
    unsigned short* Wbuf   = (unsigned short*)(out + 6 * J);      // CT*C u16

    k_wcvt<<<CT * C / 256, 256, 0, stream>>>(wconv, Wbuf);

    // wave-split channel chunks: 64-px strip per block, 4 waves = 4 chunks
    k_norm<<<2 * J / 64, 256, 0, stream>>>(x, invall);

    k_argmin<<<dim3(J / 64, 2), 256, 0, stream>>>(x, invall, sel, siv);

    k_gemm<<<J / 128, 512, 0, stream>>>(x, Wbuf, sel, siv, out);

    k_bn<<<C, 256, 0, stream>>>(out, gamma, beta);

    k_copy<<<(B * 2 * CP / 4 + 255) / 256, 256, 0, stream>>>(
        (const float4*)x, (float4*)out);
}

// Round 7
// 293.566 us; speedup vs baseline: 1.3583x; 1.3583x over previous
//
#include <hip/hip_runtime.h>

// Problem constants
constexpr int B  = 8;
constexpr int C  = 256;
constexpr int Hh = 64;
constexpr int Ww = 64;
constexpr int P  = Hh * Ww;        // 4096 pixels
constexpr int CP = C * P;          // elements per (b,t) slice
constexpr int CT = 3 * C;          // 768 concat channels
constexpr int J  = B * P;          // 32768 columns

// Per-batch scratch inside out slot-0 of batch b.
// DOT/SSQ offsets in DOUBLES from slot-0 base; IV/SEL/SIV/WB in floats.
// k_copy overwrites slots 0/1 LAST; gemm writes slot 2 only -> no overlap.
constexpr int DOT_D_OFF = 0;        // double[2][2][9][4096] (chunk,side,k,p) = 147456 d
constexpr int SSQ_D_OFF = 147456;   // double[2][2][4096]    (chunk,side,p)   = 16384 d
constexpr int IV_F_OFF  = 327680;   // float [2][4096]
constexpr int SEL_F_OFF = 335872;   // int   [2][4096]
constexpr int SIV_F_OFF = 344064;   // float [2][4096] -> ends 352256
constexpr int WB_F_OFF  = 352256;   // bf16 weights (batch-0 only), 49152 f -> 401408 < CP

typedef __attribute__((ext_vector_type(8))) short short8;
typedef __attribute__((ext_vector_type(4))) float f32x4;

__device__ inline unsigned short bf16_rne(float f) {
    unsigned u = __float_as_uint(f);
    return (unsigned short)((u + 0x7fffu + ((u >> 16) & 1u)) >> 16);
}
__device__ inline unsigned pack2(float a, float b) {
    return (unsigned)bf16_rne(a) | ((unsigned)bf16_rne(b) << 16);
}

// ---------------------------------------------------------------------------
// Kernel: convert conv weights fp32 -> bf16 (RNE), layout unchanged [m][k]
// ---------------------------------------------------------------------------
__global__ __launch_bounds__(256) void k_wcvt(const float* __restrict__ Wg,
                                              unsigned short* __restrict__ Wb) {
    int i = blockIdx.x * 256 + threadIdx.x;   // 196608 elems, grid exact
    Wb[i] = bf16_rne(Wg[i]);
}

// ---------------------------------------------------------------------------
// Kernel: fused neighbor-dots + sumsq. Counter re-analysis of rounds 0/1:
// the invariant was ~3G VMEM-requests/s (dword = 256B/wave-req), not bytes.
// Fix: stage each channel's 4KB block working set (cur 1KB + prev 1.5KB +
// next 1.5KB) as ONE float4 per thread (1KB/wave-req, 4x granule).
// Block = 4-row strip (256 px) x 128-ch chunk, both sides fused; LDS
// double-buffer, 2-deep register prefetch, one syncthreads per channel.
// (Round-6 crash root-caused: strip*1024 byte-offset applied to float
// pointer => OOB read; fixed to strip*256.)
// Partials (18 dots + 2 sumsq, fp64) -> per-batch scratch; fixed chunk-sum
// order downstream => clipped-duplicate neighbors bit-identical => strict-<
// first-min tie-break preserved.
// ---------------------------------------------------------------------------
__global__ __launch_bounds__(256) void k_dots(const float* __restrict__ x,
                                              float* __restrict__ out) {
    __shared__ float ys[2][2][6][64];   // [buf][side][row][x] 6 KB
    __shared__ float cs[2][256];        // [buf][px]            2 KB
    const int t     = threadIdx.x;
    const int b     = blockIdx.x >> 4;
    const int strip = blockIdx.x & 15;
    const int chunk = blockIdx.y;       // 0..1 -> channels [128*chunk, +128)
    const int y0 = strip * 4;
    const int ry = t >> 6;              // own row in strip (0..3)
    const int xc = t & 63;
    const int xm = max(xc - 1, 0), xp = min(xc + 1, 63);
    const int c0 = chunk * 128;

    // one float4 staging slot per thread: 64 cur + 96 prev + 96 next = 256
    size_t gbase; int l0;               // LDS float offset (per buf)
    if (t < 64) {
        // cur strip: pixel offset strip*256 + t*4 (FLOAT units)
        gbase = (size_t)(b * 3 + 2) * CP + (size_t)c0 * P + strip * 256 + t * 4;
        l0 = t * 4;                     // cs slot
    } else {
        int i   = t - 64;               // 0..191
        int sid = i >= 96;              // 0=prev, 1=next
        int r   = (i - sid * 96) >> 4;  // staged row 0..5
        int x4  = i & 15;               // 96 = 6*16 -> (i-96)&15 == i&15
        int yl  = min(max(y0 - 1 + r, 0), Hh - 1);
        gbase = (size_t)(b * 3 + sid) * CP + (size_t)c0 * P + yl * 64 + x4 * 4;
        l0 = (sid * 6 + r) * 64 + x4 * 4;
    }
    float* ysf = &ys[0][0][0][0];       // flat view; buf stride = 768 floats
    float* dst0 = (t < 64) ? &cs[0][l0] : &ysf[l0];
    float* dst1 = (t < 64) ? &cs[1][l0] : &ysf[768 + l0];

    double d[2][9] = {{0,0,0,0,0,0,0,0,0},{0,0,0,0,0,0,0,0,0}};
    double qs[2] = {0.0, 0.0};

    f32x4 r0 = *(const f32x4*)(x + gbase);                  // chan 0
    f32x4 r1 = *(const f32x4*)(x + gbase + (size_t)P);      // chan 1

    #define COMPUTE(BUF)                                                     \
    {                                                                        \
        double cd = (double)cs[BUF][t];                                      \
        _Pragma("unroll")                                                    \
        for (int s = 0; s < 2; ++s) {                                        \
            const float* Y0 = &ys[BUF][s][ry][0];     /* own y - 1 */        \
            const float* Y1 = Y0 + 64;                /* own y     */        \
            const float* Y2 = Y1 + 64;                /* own y + 1 */        \
            d[s][0] = fma(cd, (double)Y0[xm], d[s][0]);                      \
            d[s][1] = fma(cd, (double)Y0[xc], d[s][1]);                      \
            d[s][2] = fma(cd, (double)Y0[xp], d[s][2]);                      \
            d[s][3] = fma(cd, (double)Y1[xm], d[s][3]);                      \
            d[s][4] = fma(cd, (double)Y1[xc], d[s][4]);                      \
            d[s][5] = fma(cd, (double)Y1[xp], d[s][5]);                      \
            d[s][6] = fma(cd, (double)Y2[xm], d[s][6]);                      \
            d[s][7] = fma(cd, (double)Y2[xc], d[s][7]);                      \
            d[s][8] = fma(cd, (double)Y2[xp], d[s][8]);                      \
            double ov = (double)Y1[xc];                                      \
            qs[s] = fma(ov, ov, qs[s]);                                      \
        }                                                                    \
    }

    for (int n = 0; n < 128; n += 2) {
        *(f32x4*)dst0 = r0;                 // chan n   -> buf0 (waits r0)
        __syncthreads();                    // buf0 visible; compute(n-2) done
        if (n + 2 < 128)
            r0 = *(const f32x4*)(x + gbase + (size_t)(n + 2) * P);
        COMPUTE(0)                          // chan n
        *(f32x4*)dst1 = r1;                 // chan n+1 -> buf1 (waits r1)
        __syncthreads();                    // buf1 visible; compute(n-1) done
        if (n + 3 < 128)
            r1 = *(const f32x4*)(x + gbase + (size_t)(n + 3) * P);
        COMPUTE(1)                          // chan n+1
    }
    #undef COMPUTE

    const int p = strip * 256 + t;
    double* db = (double*)(out + (size_t)(b * 3) * CP);
    #pragma unroll
    for (int s = 0; s < 2; ++s) {
        #pragma unroll
        for (int k = 0; k < 9; ++k)
            db[DOT_D_OFF + (size_t)((chunk * 2 + s) * 9 + k) * 4096 + p] = d[s][k];
        db[SSQ_D_OFF + (size_t)(chunk * 2 + s) * 4096 + p] = qs[s];
    }
}

// ---------------------------------------------------------------------------
// Kernel: inv L2 norms from sumsq partials (fixed chunk-order fp64 sum)
// ---------------------------------------------------------------------------
__global__ __launch_bounds__(256) void k_iv(float* __restrict__ out) {
    int gid  = blockIdx.x * 256 + threadIdx.x;   // 0..65535
    int side = gid >> 15;
    int j    = gid & (J - 1);
    int b = j >> 12, p = j & (P - 1);
    const double* sb = (const double*)(out + (size_t)(b * 3) * CP) + SSQ_D_OFF;
    double ssum = sb[(0 * 2 + side) * 4096 + p]
                + sb[(1 * 2 + side) * 4096 + p];
    float* ivb = out + (size_t)(b * 3) * CP + IV_F_OFF;
    ivb[side * 4096 + p] = 1.0f / fmaxf((float)sqrt(ssum), 1e-12f);
}

// ---------------------------------------------------------------------------
// Kernel: final argmin over 9 neighbors (fixed chunk-order fp64 sum;
// duplicates bit-identical; strict < = first-min tie-break)
// ---------------------------------------------------------------------------
__global__ __launch_bounds__(256) void k_sel(float* __restrict__ out) {
    int gid  = blockIdx.x * 256 + threadIdx.x;
    int side = gid >> 15;
    int j    = gid & (J - 1);
    int b = j >> 12, p = j & (P - 1);
    int y = p >> 6, xc = p & 63;

    int nidx[9];
    #pragma unroll
    for (int k = 0; k < 9; ++k) {
        int dy = k / 3 - 1, dx = k % 3 - 1;     // y_off=repeat, x_off=tile
        int yy = min(max(y + dy, 0), Hh - 1);
        int xx = min(max(xc + dx, 0), Ww - 1);
        nidx[k] = yy * Ww + xx;
    }

    const double* db  = (const double*)(out + (size_t)(b * 3) * CP) + DOT_D_OFF;
    const float*  ivb = out + (size_t)(b * 3) * CP + IV_F_OFF;

    double best = 0.0; int bi = 0;
    #pragma unroll
    for (int k = 0; k < 9; ++k) {
        double sk = db[(size_t)((0 * 2 + side) * 9 + k) * 4096 + p]
                  + db[(size_t)((1 * 2 + side) * 9 + k) * 4096 + p];
        double s = sk * (double)ivb[side * 4096 + nidx[k]];
        if (k == 0 || s < best) { best = s; bi = k; }
    }
    int*   selb = (int*)(out + (size_t)(b * 3) * CP + SEL_F_OFF);
    float* sivb = out + (size_t)(b * 3) * CP + SIV_F_OFF;
    selb[side * 4096 + p] = nidx[bi];
    sivb[side * 4096 + p] = ivb[side * 4096 + nidx[bi]];
}

// ---------------------------------------------------------------------------
// Kernel: bf16 MFMA GEMM with fused gather+normalize+cvt of the feature
// matrix. C[m=256][j-tile of 128] = sum_k W[m][k] * F(k,j), K = 768.
// Grid: 256 blocks (J/128), 512 threads (8 waves; wave = 64m x 64n subtile;
// 4x4 frags of mfma_f32_16x16x32_bf16). sel/siv from per-batch scratch.
// ---------------------------------------------------------------------------
__global__ __launch_bounds__(512) void k_gemm(const float* __restrict__ x,
                                              const unsigned short* __restrict__ Wb,
                                              float* __restrict__ out) {
    __shared__ unsigned short As[4][256][8];   // 16 KB, k-octet blocked
    __shared__ unsigned short Bs[4][128][8];   // 8 KB
    __shared__ int   sel_s[2][128];
    __shared__ float siv_s[2][128];

    const int t  = threadIdx.x;
    const int j0 = blockIdx.x * 128;
    const int b  = j0 >> 12, p0 = j0 & (P - 1);   // 128 | 4096 -> b uniform

    if (t < 256) {
        int side = t >> 7, jj = t & 127;
        const int*   selb = (const int*)(out + (size_t)(b * 3) * CP + SEL_F_OFF);
        const float* sivb = out + (size_t)(b * 3) * CP + SIV_F_OFF;
        sel_s[side][jj] = selb[side * 4096 + p0 + jj];
        siv_s[side][jj] = sivb[side * 4096 + p0 + jj];
    }
    __syncthreads();

    const float* prevb = x + (size_t)(b * 3 + 0) * CP;
    const float* nextb = x + (size_t)(b * 3 + 1) * CP;
    const float* curb  = x + (size_t)(b * 3 + 2) * CP;

    const int lane = t & 63, w = t >> 6;
    const int q = lane >> 4, l16 = lane & 15;
    const int m0w = (w & 3) * 64;      // 4 m-quadrants of 256
    const int n0w = (w >> 2) * 64;     // 2 n-halves of 128

    const int jj = t & 127, kq = (t >> 7) & 3;   // B staging role
    const int ma = t & 255, kh = t >> 8;         // A staging role

    f32x4 acc[4][4];
    #pragma unroll
    for (int f = 0; f < 4; ++f)
        #pragma unroll
        for (int g = 0; g < 4; ++g)
            acc[f][g] = (f32x4){0.f, 0.f, 0.f, 0.f};

    for (int kk = 0; kk < CT; kk += 32) {
        // --- global loads into regs (no LDS yet) ---
        const unsigned short* wsrc = Wb + (size_t)ma * CT + kk + kh * 16;
        short8 wa0 = *(const short8*)wsrc;
        short8 wa1 = *(const short8*)(wsrc + 8);

        const float* src; float scale;
        int k0 = kq * 8;
        if (kk < 256) {
            src = prevb + (size_t)(kk + k0) * P + sel_s[0][jj];
            scale = siv_s[0][jj];
        } else if (kk < 512) {
            src = nextb + (size_t)(kk - 256 + k0) * P + sel_s[1][jj];
            scale = siv_s[1][jj];
        } else {
            src = curb + (size_t)(kk - 512 + k0) * P + p0 + jj;
            scale = 1.0f;
        }
        float f0 = src[0] * scale,             f1 = src[(size_t)P] * scale;
        float f2 = src[(size_t)2 * P] * scale, f3 = src[(size_t)3 * P] * scale;
        float f4 = src[(size_t)4 * P] * scale, f5 = src[(size_t)5 * P] * scale;
        float f6 = src[(size_t)6 * P] * scale, f7 = src[(size_t)7 * P] * scale;

        __syncthreads();   // prior iteration done reading LDS

        *(short8*)&As[kh * 2    ][ma][0] = wa0;
        *(short8*)&As[kh * 2 + 1][ma][0] = wa1;
        uint4 pk = make_uint4(pack2(f0, f1), pack2(f2, f3),
                              pack2(f4, f5), pack2(f6, f7));
        *(uint4*)&Bs[kq][jj][0] = pk;

        __syncthreads();

        short8 af[4], bfr[4];
        #pragma unroll
        for (int f = 0; f < 4; ++f)
            af[f] = *(const short8*)&As[q][m0w + f * 16 + l16][0];
        #pragma unroll
        for (int g = 0; g < 4; ++g)
            bfr[g] = *(const short8*)&Bs[q][n0w + g * 16 + l16][0];
        #pragma unroll
        for (int f = 0; f < 4; ++f)
            #pragma unroll
            for (int g = 0; g < 4; ++g)
                acc[f][g] = __builtin_amdgcn_mfma_f32_16x16x32_bf16(
                    af[f], bfr[g], acc[f][g], 0, 0, 0);
    }

    // epilogue: D[row=q*4+r][col=l16] per 16x16 frag (measured C/D layout)
    float* outb = out + (size_t)(b * 3 + 2) * CP;
    #pragma unroll
    for (int f = 0; f < 4; ++f)
        #pragma unroll
        for (int g = 0; g < 4; ++g)
            #pragma unroll
            for (int r = 0; r < 4; ++r) {
                int ch  = m0w + f * 16 + q * 4 + r;
                int col = p0 + n0w + g * 16 + l16;
                outb[(size_t)ch * P + col] = acc[f][g][r];
            }
}

// ---------------------------------------------------------------------------
// Kernel: per-channel BN stats + normalize + ReLU in place on out slot 2
// ---------------------------------------------------------------------------
__global__ __launch_bounds__(256) void k_bn(float* __restrict__ out,
                                            const float* __restrict__ gamma,
                                            const float* __restrict__ beta) {
    __shared__ double rs[256], rq[256];
    __shared__ float sc_s, sh_s;
    const int o = blockIdx.x, t = threadIdx.x;

    double s = 0.0, q = 0.0;
    for (int b = 0; b < B; ++b) {
        const float4* base =
            (const float4*)(out + (size_t)(b * 3 + 2) * CP + (size_t)o * P);
        #pragma unroll
        for (int i = 0; i < 4; ++i) {
            float4 v = base[i * 256 + t];
            s += (double)v.x + (double)v.y + (double)v.z + (double)v.w;
            q += (double)v.x * v.x + (double)v.y * v.y
               + (double)v.z * v.z + (double)v.w * v.w;
        }
    }
    rs[t] = s; rq[t] = q;
    __syncthreads();
    for (int off = 128; off > 0; off >>= 1) {
        if (t < off) { rs[t] += rs[t + off]; rq[t] += rq[t + off]; }
        __syncthreads();
    }
    if (t == 0) {
        double mean = rs[0] * (1.0 / (double)J);
        double var  = rq[0] * (1.0 / (double)J) - mean * mean;
        double inv  = 1.0 / sqrt(var + 1e-5);
        double sc   = (double)gamma[o] * inv;
        sc_s = (float)sc;
        sh_s = (float)((double)beta[o] - mean * sc);
    }
    __syncthreads();
    const float sc = sc_s, sh = sh_s;

    for (int b = 0; b < B; ++b) {
        float4* base =
            (float4*)(out + (size_t)(b * 3 + 2) * CP + (size_t)o * P);
        #pragma unroll
        for (int i = 0; i < 4; ++i) {
            float4 v = base[i * 256 + t];
            v.x = fmaxf(fmaf(v.x, sc, sh), 0.f);
            v.y = fmaxf(fmaf(v.y, sc, sh), 0.f);
            v.z = fmaxf(fmaf(v.z, sc, sh), 0.f);
            v.w = fmaxf(fmaf(v.w, sc, sh), 0.f);
            base[i * 256 + t] = v;
        }
    }
}

// ---------------------------------------------------------------------------
// Kernel: copy prev/next slices to output slots 0/1 (runs LAST: overwrites
// the scratch region used by earlier kernels)
// ---------------------------------------------------------------------------
__global__ __launch_bounds__(256) void k_copy(const float4* __restrict__ x4,
                                              float4* __restrict__ o4) {
    int tid = blockIdx.x * blockDim.x + threadIdx.x;
    const int per_b = 2 * CP / 4;
    const int bstr  = 3 * CP / 4;
    if (tid < B * per_b) {
        int b = tid / per_b;
        int r = tid - b * per_b;
        o4[b * bstr + r] = x4[b * bstr + r];
    }
}

// ---------------------------------------------------------------------------
extern "C" void kernel_launch(void* const* d_in, const int* in_sizes, int n_in,
                              void* d_out, int out_size, void* d_ws, size_t ws_size,
                              hipStream_t stream) {
    const float* x     = (const float*)d_in[0];
    const float* wconv = (const float*)d_in[1];
    const float* gamma = (const float*)d_in[2];
    const float* beta  = (const float*)d_in[3];
    float* out = (float*)d_out;
    (void)d_ws; (void)ws_size;   // deliberately unused

    unsigned short* Wbuf = (unsigned short*)(out + WB_F_OFF);

    k_wcvt<<<CT * C / 256, 256, 0, stream>>>(wconv, Wbuf);

    // fused dots+sumsq: (8 batches x 16 strips) x 2 channel chunks
    k_dots<<<dim3(128, 2), 256, 0, stream>>>(x, out);

    k_iv<<<2 * J / 256, 256, 0, stream>>>(out);

    k_sel<<<2 * J / 256, 256, 0, stream>>>(out);

    k_gemm<<<J / 128, 512, 0, stream>>>(x, Wbuf, out);

    k_bn<<<C, 256, 0, stream>>>(out, gamma, beta);

    k_copy<<<(B * 2 * CP / 4 + 255) / 256, 256, 0, stream>>>(
        (const float4*)x, (float4*)out);
}

// Round 8
// 268.748 us; speedup vs baseline: 1.4838x; 1.0923x over previous
//
#include <hip/hip_runtime.h>

// Problem constants
constexpr int B  = 8;
constexpr int C  = 256;
constexpr int Hh = 64;
constexpr int Ww = 64;
constexpr int P  = Hh * Ww;        // 4096 pixels
constexpr int CP = C * P;          // elements per (b,t) slice
constexpr int CT = 3 * C;          // 768 concat channels
constexpr int J  = B * P;          // 32768 columns

// Per-batch scratch inside out slot-0 of batch b (4-chunk layout).
// DOT/SSQ offsets in DOUBLES from slot-0 base; IV/SEL/SIV/WB in floats.
// k_copy overwrites slots 0/1 LAST; gemm writes slot 2 only -> no overlap.
constexpr int DOT_D_OFF = 0;        // double[4][2][9][4096] (chunk,side,k,p) = 294912 d
constexpr int SSQ_D_OFF = 294912;   // double[4][2][4096]    (chunk,side,p)   = 32768 d
constexpr int IV_F_OFF  = 655360;   // float [2][4096]
constexpr int SEL_F_OFF = 663552;   // int   [2][4096]
constexpr int SIV_F_OFF = 671744;   // float [2][4096] -> ends 679936
constexpr int WB_F_OFF  = 679936;   // bf16 weights (batch-0 only), 49152 f -> 729088 < CP

typedef __attribute__((ext_vector_type(8))) short short8;
typedef __attribute__((ext_vector_type(4))) float f32x4;

__device__ inline unsigned short bf16_rne(float f) {
    unsigned u = __float_as_uint(f);
    return (unsigned short)((u + 0x7fffu + ((u >> 16) & 1u)) >> 16);
}
__device__ inline unsigned pack2(float a, float b) {
    return (unsigned)bf16_rne(a) | ((unsigned)bf16_rne(b) << 16);
}

// ---------------------------------------------------------------------------
// Kernel: convert conv weights fp32 -> bf16 (RNE), layout unchanged [m][k]
// ---------------------------------------------------------------------------
__global__ __launch_bounds__(256) void k_wcvt(const float* __restrict__ Wg,
                                              unsigned short* __restrict__ Wb) {
    int i = blockIdx.x * 256 + threadIdx.x;   // 196608 elems, grid exact
    Wb[i] = bf16_rne(Wg[i]);
}

// ---------------------------------------------------------------------------
// Kernel: fused neighbor-dots + sumsq. Round-7 result: float4 staging lifted
// per-byte efficiency (838 GB/s -> 1 TB/s), but occupancy 9.9% (1 block/CU,
// lockstep barriers, ~4-8KB in flight vs ~10KB needed) capped BW. Fix:
// 4-way channel chunks (64 ch) -> 512 blocks = 2 independent blocks/CU,
// doubling outstanding loads. Same staging: block = 4-row strip (256 px),
// each channel's working set (cur 1KB + prev 1.5KB + next 1.5KB) = one
// float4 per thread; LDS double-buffer, 2-deep register prefetch, one
// syncthreads per channel. Partials (18 dots + 2 sumsq, fp64) -> per-batch
// scratch; fixed chunk-sum order downstream => clipped-duplicate neighbors
// bit-identical => strict-< first-min tie-break preserved.
// ---------------------------------------------------------------------------
__global__ __launch_bounds__(256) void k_dots(const float* __restrict__ x,
                                              float* __restrict__ out) {
    __shared__ float ys[2][2][6][64];   // [buf][side][row][x] 6 KB
    __shared__ float cs[2][256];        // [buf][px]            2 KB
    const int t     = threadIdx.x;
    const int b     = blockIdx.x >> 4;
    const int strip = blockIdx.x & 15;
    const int chunk = blockIdx.y;       // 0..3 -> channels [64*chunk, +64)
    const int y0 = strip * 4;
    const int ry = t >> 6;              // own row in strip (0..3)
    const int xc = t & 63;
    const int xm = max(xc - 1, 0), xp = min(xc + 1, 63);
    const int c0 = chunk * 64;

    // one float4 staging slot per thread: 64 cur + 96 prev + 96 next = 256
    size_t gbase; int l0;               // LDS float offset (per buf)
    if (t < 64) {
        // cur strip: pixel offset strip*256 + t*4 (FLOAT units)
        gbase = (size_t)(b * 3 + 2) * CP + (size_t)c0 * P + strip * 256 + t * 4;
        l0 = t * 4;                     // cs slot
    } else {
        int i   = t - 64;               // 0..191
        int sid = i >= 96;              // 0=prev, 1=next
        int r   = (i - sid * 96) >> 4;  // staged row 0..5
        int x4  = i & 15;               // 96 = 6*16 -> (i-96)&15 == i&15
        int yl  = min(max(y0 - 1 + r, 0), Hh - 1);
        gbase = (size_t)(b * 3 + sid) * CP + (size_t)c0 * P + yl * 64 + x4 * 4;
        l0 = (sid * 6 + r) * 64 + x4 * 4;
    }
    float* ysf = &ys[0][0][0][0];       // flat view; buf stride = 768 floats
    float* dst0 = (t < 64) ? &cs[0][l0] : &ysf[l0];
    float* dst1 = (t < 64) ? &cs[1][l0] : &ysf[768 + l0];

    double d[2][9] = {{0,0,0,0,0,0,0,0,0},{0,0,0,0,0,0,0,0,0}};
    double qs[2] = {0.0, 0.0};

    f32x4 r0 = *(const f32x4*)(x + gbase);                  // chan 0
    f32x4 r1 = *(const f32x4*)(x + gbase + (size_t)P);      // chan 1

    #define COMPUTE(BUF)                                                     \
    {                                                                        \
        double cd = (double)cs[BUF][t];                                      \
        _Pragma("unroll")                                                    \
        for (int s = 0; s < 2; ++s) {                                        \
            const float* Y0 = &ys[BUF][s][ry][0];     /* own y - 1 */        \
            const float* Y1 = Y0 + 64;                /* own y     */        \
            const float* Y2 = Y1 + 64;                /* own y + 1 */        \
            d[s][0] = fma(cd, (double)Y0[xm], d[s][0]);                      \
            d[s][1] = fma(cd, (double)Y0[xc], d[s][1]);                      \
            d[s][2] = fma(cd, (double)Y0[xp], d[s][2]);                      \
            d[s][3] = fma(cd, (double)Y1[xm], d[s][3]);                      \
            d[s][4] = fma(cd, (double)Y1[xc], d[s][4]);                      \
            d[s][5] = fma(cd, (double)Y1[xp], d[s][5]);                      \
            d[s][6] = fma(cd, (double)Y2[xm], d[s][6]);                      \
            d[s][7] = fma(cd, (double)Y2[xc], d[s][7]);                      \
            d[s][8] = fma(cd, (double)Y2[xp], d[s][8]);                      \
            double ov = (double)Y1[xc];                                      \
            qs[s] = fma(ov, ov, qs[s]);                                      \
        }                                                                    \
    }

    for (int n = 0; n < 64; n += 2) {
        *(f32x4*)dst0 = r0;                 // chan n   -> buf0 (waits r0)
        __syncthreads();                    // buf0 visible; compute(n-2) done
        if (n + 2 < 64)
            r0 = *(const f32x4*)(x + gbase + (size_t)(n + 2) * P);
        COMPUTE(0)                          // chan n
        *(f32x4*)dst1 = r1;                 // chan n+1 -> buf1 (waits r1)
        __syncthreads();                    // buf1 visible; compute(n-1) done
        if (n + 3 < 64)
            r1 = *(const f32x4*)(x + gbase + (size_t)(n + 3) * P);
        COMPUTE(1)                          // chan n+1
    }
    #undef COMPUTE

    const int p = strip * 256 + t;
    double* db = (double*)(out + (size_t)(b * 3) * CP);
    #pragma unroll
    for (int s = 0; s < 2; ++s) {
        #pragma unroll
        for (int k = 0; k < 9; ++k)
            db[DOT_D_OFF + (size_t)((chunk * 2 + s) * 9 + k) * 4096 + p] = d[s][k];
        db[SSQ_D_OFF + (size_t)(chunk * 2 + s) * 4096 + p] = qs[s];
    }
}

// ---------------------------------------------------------------------------
// Kernel: inv L2 norms from sumsq partials (fixed chunk-order fp64 sum)
// ---------------------------------------------------------------------------
__global__ __launch_bounds__(256) void k_iv(float* __restrict__ out) {
    int gid  = blockIdx.x * 256 + threadIdx.x;   // 0..65535
    int side = gid >> 15;
    int j    = gid & (J - 1);
    int b = j >> 12, p = j & (P - 1);
    const double* sb = (const double*)(out + (size_t)(b * 3) * CP) + SSQ_D_OFF;
    double ssum = ((sb[(0 * 2 + side) * 4096 + p]
                  + sb[(1 * 2 + side) * 4096 + p])
                  + sb[(2 * 2 + side) * 4096 + p])
                  + sb[(3 * 2 + side) * 4096 + p];
    float* ivb = out + (size_t)(b * 3) * CP + IV_F_OFF;
    ivb[side * 4096 + p] = 1.0f / fmaxf((float)sqrt(ssum), 1e-12f);
}

// ---------------------------------------------------------------------------
// Kernel: final argmin over 9 neighbors (fixed chunk-order fp64 sum;
// duplicates bit-identical; strict < = first-min tie-break)
// ---------------------------------------------------------------------------
__global__ __launch_bounds__(256) void k_sel(float* __restrict__ out) {
    int gid  = blockIdx.x * 256 + threadIdx.x;
    int side = gid >> 15;
    int j    = gid & (J - 1);
    int b = j >> 12, p = j & (P - 1);
    int y = p >> 6, xc = p & 63;

    int nidx[9];
    #pragma unroll
    for (int k = 0; k < 9; ++k) {
        int dy = k / 3 - 1, dx = k % 3 - 1;     // y_off=repeat, x_off=tile
        int yy = min(max(y + dy, 0), Hh - 1);
        int xx = min(max(xc + dx, 0), Ww - 1);
        nidx[k] = yy * Ww + xx;
    }

    const double* db  = (const double*)(out + (size_t)(b * 3) * CP) + DOT_D_OFF;
    const float*  ivb = out + (size_t)(b * 3) * CP + IV_F_OFF;

    double best = 0.0; int bi = 0;
    #pragma unroll
    for (int k = 0; k < 9; ++k) {
        double sk = ((db[(size_t)((0 * 2 + side) * 9 + k) * 4096 + p]
                    + db[(size_t)((1 * 2 + side) * 9 + k) * 4096 + p])
                    + db[(size_t)((2 * 2 + side) * 9 + k) * 4096 + p])
                    + db[(size_t)((3 * 2 + side) * 9 + k) * 4096 + p];
        double s = sk * (double)ivb[side * 4096 + nidx[k]];
        if (k == 0 || s < best) { best = s; bi = k; }
    }
    int*   selb = (int*)(out + (size_t)(b * 3) * CP + SEL_F_OFF);
    float* sivb = out + (size_t)(b * 3) * CP + SIV_F_OFF;
    selb[side * 4096 + p] = nidx[bi];
    sivb[side * 4096 + p] = ivb[side * 4096 + nidx[bi]];
}

// ---------------------------------------------------------------------------
// Kernel: bf16 MFMA GEMM with fused gather+normalize+cvt of the feature
// matrix. C[m=256][j-tile of 128] = sum_k W[m][k] * F(k,j), K = 768.
// Grid: 256 blocks (J/128), 512 threads (8 waves; wave = 64m x 64n subtile;
// 4x4 frags of mfma_f32_16x16x32_bf16). sel/siv from per-batch scratch.
// ---------------------------------------------------------------------------
__global__ __launch_bounds__(512) void k_gemm(const float* __restrict__ x,
                                              const unsigned short* __restrict__ Wb,
                                              float* __restrict__ out) {
    __shared__ unsigned short As[4][256][8];   // 16 KB, k-octet blocked
    __shared__ unsigned short Bs[4][128][8];   // 8 KB
    __shared__ int   sel_s[2][128];
    __shared__ float siv_s[2][128];

    const int t  = threadIdx.x;
    const int j0 = blockIdx.x * 128;
    const int b  = j0 >> 12, p0 = j0 & (P - 1);   // 128 | 4096 -> b uniform

    if (t < 256) {
        int side = t >> 7, jj = t & 127;
        const int*   selb = (const int*)(out + (size_t)(b * 3) * CP + SEL_F_OFF);
        const float* sivb = out + (size_t)(b * 3) * CP + SIV_F_OFF;
        sel_s[side][jj] = selb[side * 4096 + p0 + jj];
        siv_s[side][jj] = sivb[side * 4096 + p0 + jj];
    }
    __syncthreads();

    const float* prevb = x + (size_t)(b * 3 + 0) * CP;
    const float* nextb = x + (size_t)(b * 3 + 1) * CP;
    const float* curb  = x + (size_t)(b * 3 + 2) * CP;

    const int lane = t & 63, w = t >> 6;
    const int q = lane >> 4, l16 = lane & 15;
    const int m0w = (w & 3) * 64;      // 4 m-quadrants of 256
    const int n0w = (w >> 2) * 64;     // 2 n-halves of 128

    const int jj = t & 127, kq = (t >> 7) & 3;   // B staging role
    const int ma = t & 255, kh = t >> 8;         // A staging role

    f32x4 acc[4][4];
    #pragma unroll
    for (int f = 0; f < 4; ++f)
        #pragma unroll
        for (int g = 0; g < 4; ++g)
            acc[f][g] = (f32x4){0.f, 0.f, 0.f, 0.f};

    for (int kk = 0; kk < CT; kk += 32) {
        // --- global loads into regs (no LDS yet) ---
        const unsigned short* wsrc = Wb + (size_t)ma * CT + kk + kh * 16;
        short8 wa0 = *(const short8*)wsrc;
        short8 wa1 = *(const short8*)(wsrc + 8);

        const float* src; float scale;
        int k0 = kq * 8;
        if (kk < 256) {
            src = prevb + (size_t)(kk + k0) * P + sel_s[0][jj];
            scale = siv_s[0][jj];
        } else if (kk < 512) {
            src = nextb + (size_t)(kk - 256 + k0) * P + sel_s[1][jj];
            scale = siv_s[1][jj];
        } else {
            src = curb + (size_t)(kk - 512 + k0) * P + p0 + jj;
            scale = 1.0f;
        }
        float f0 = src[0] * scale,             f1 = src[(size_t)P] * scale;
        float f2 = src[(size_t)2 * P] * scale, f3 = src[(size_t)3 * P] * scale;
        float f4 = src[(size_t)4 * P] * scale, f5 = src[(size_t)5 * P] * scale;
        float f6 = src[(size_t)6 * P] * scale, f7 = src[(size_t)7 * P] * scale;

        __syncthreads();   // prior iteration done reading LDS

        *(short8*)&As[kh * 2    ][ma][0] = wa0;
        *(short8*)&As[kh * 2 + 1][ma][0] = wa1;
        uint4 pk = make_uint4(pack2(f0, f1), pack2(f2, f3),
                              pack2(f4, f5), pack2(f6, f7));
        *(uint4*)&Bs[kq][jj][0] = pk;

        __syncthreads();

        short8 af[4], bfr[4];
        #pragma unroll
        for (int f = 0; f < 4; ++f)
            af[f] = *(const short8*)&As[q][m0w + f * 16 + l16][0];
        #pragma unroll
        for (int g = 0; g < 4; ++g)
            bfr[g] = *(const short8*)&Bs[q][n0w + g * 16 + l16][0];
        #pragma unroll
        for (int f = 0; f < 4; ++f)
            #pragma unroll
            for (int g = 0; g < 4; ++g)
                acc[f][g] = __builtin_amdgcn_mfma_f32_16x16x32_bf16(
                    af[f], bfr[g], acc[f][g], 0, 0, 0);
    }

    // epilogue: D[row=q*4+r][col=l16] per 16x16 frag (measured C/D layout)
    float* outb = out + (size_t)(b * 3 + 2) * CP;
    #pragma unroll
    for (int f = 0; f < 4; ++f)
        #pragma unroll
        for (int g = 0; g < 4; ++g)
            #pragma unroll
            for (int r = 0; r < 4; ++r) {
                int ch  = m0w + f * 16 + q * 4 + r;
                int col = p0 + n0w + g * 16 + l16;
                outb[(size_t)ch * P + col] = acc[f][g][r];
            }
}

// ---------------------------------------------------------------------------
// Kernel: per-channel BN stats + normalize + ReLU in place on out slot 2
// ---------------------------------------------------------------------------
__global__ __launch_bounds__(256) void k_bn(float* __restrict__ out,
                                            const float* __restrict__ gamma,
                                            const float* __restrict__ beta) {
    __shared__ double rs[256], rq[256];
    __shared__ float sc_s, sh_s;
    const int o = blockIdx.x, t = threadIdx.x;

    double s = 0.0, q = 0.0;
    for (int b = 0; b < B; ++b) {
        const float4* base =
            (const float4*)(out + (size_t)(b * 3 + 2) * CP + (size_t)o * P);
        #pragma unroll
        for (int i = 0; i < 4; ++i) {
            float4 v = base[i * 256 + t];
            s += (double)v.x + (double)v.y + (double)v.z + (double)v.w;
            q += (double)v.x * v.x + (double)v.y * v.y
               + (double)v.z * v.z + (double)v.w * v.w;
        }
    }
    rs[t] = s; rq[t] = q;
    __syncthreads();
    for (int off = 128; off > 0; off >>= 1) {
        if (t < off) { rs[t] += rs[t + off]; rq[t] += rq[t + off]; }
        __syncthreads();
    }
    if (t == 0) {
        double mean = rs[0] * (1.0 / (double)J);
        double var  = rq[0] * (1.0 / (double)J) - mean * mean;
        double inv  = 1.0 / sqrt(var + 1e-5);
        double sc   = (double)gamma[o] * inv;
        sc_s = (float)sc;
        sh_s = (float)((double)beta[o] - mean * sc);
    }
    __syncthreads();
    const float sc = sc_s, sh = sh_s;

    for (int b = 0; b < B; ++b) {
        float4* base =
            (float4*)(out + (size_t)(b * 3 + 2) * CP + (size_t)o * P);
        #pragma unroll
        for (int i = 0; i < 4; ++i) {
            float4 v = base[i * 256 + t];
            v.x = fmaxf(fmaf(v.x, sc, sh), 0.f);
            v.y = fmaxf(fmaf(v.y, sc, sh), 0.f);
            v.z = fmaxf(fmaf(v.z, sc, sh), 0.f);
            v.w = fmaxf(fmaf(v.w, sc, sh), 0.f);
            base[i * 256 + t] = v;
        }
    }
}

// ---------------------------------------------------------------------------
// Kernel: copy prev/next slices to output slots 0/1 (runs LAST: overwrites
// the scratch region used by earlier kernels)
// ---------------------------------------------------------------------------
__global__ __launch_bounds__(256) void k_copy(const float4* __restrict__ x4,
                                              float4* __restrict__ o4) {
    int tid = blockIdx.x * blockDim.x + threadIdx.x;
    const int per_b = 2 * CP / 4;
    const int bstr  = 3 * CP / 4;
    if (tid < B * per_b) {
        int b = tid / per_b;
        int r = tid - b * per_b;
        o4[b * bstr + r] = x4[b * bstr + r];
    }
}

// ---------------------------------------------------------------------------
extern "C" void kernel_launch(void* const* d_in, const int* in_sizes, int n_in,
                              void* d_out, int out_size, void* d_ws, size_t ws_size,
                              hipStream_t stream) {
    const float* x     = (const float*)d_in[0];
    const float* wconv = (const float*)d_in[1];
    const float* gamma = (const float*)d_in[2];
    const float* beta  = (const float*)d_in[3];
    float* out = (float*)d_out;
    (void)d_ws; (void)ws_size;   // deliberately unused

    unsigned short* Wbuf = (unsigned short*)(out + WB_F_OFF);

    k_wcvt<<<CT * C / 256, 256, 0, stream>>>(wconv, Wbuf);

    // fused dots+sumsq: (8 batches x 16 strips) x 4 channel chunks
    k_dots<<<dim3(128, 4), 256, 0, stream>>>(x, out);

    k_iv<<<2 * J / 256, 256, 0, stream>>>(out);

    k_sel<<<2 * J / 256, 256, 0, stream>>>(out);

    k_gemm<<<J / 128, 512, 0, stream>>>(x, Wbuf, out);

    k_bn<<<C, 256, 0, stream>>>(out, gamma, beta);

    k_copy<<<(B * 2 * CP / 4 + 255) / 256, 256, 0, stream>>>(
        (const float4*)x, (float4*)out);
}

// Round 10
// 267.487 us; speedup vs baseline: 1.4908x; 1.0047x over previous
//
#include <hip/hip_runtime.h>

// Problem constants
constexpr int B  = 8;
constexpr int C  = 256;
constexpr int Hh = 64;
constexpr int Ww = 64;
constexpr int P  = Hh * Ww;        // 4096 pixels
constexpr int CP = C * P;          // elements per (b,t) slice
constexpr int CT = 3 * C;          // 768 concat channels
constexpr int J  = B * P;          // 32768 columns

// Per-batch scratch inside out slot-0 of batch b (4-chunk layout).
// DOT/SSQ offsets in DOUBLES from slot-0 base; IV/SEL/SIV/WB in floats.
// k_copy overwrites slots 0/1 LAST; gemm writes slot 2 only -> no overlap.
constexpr int DOT_D_OFF = 0;        // double[4][2][9][4096] (chunk,side,k,p) = 294912 d
constexpr int SSQ_D_OFF = 294912;   // double[4][2][4096]    (chunk,side,p)   = 32768 d
constexpr int IV_F_OFF  = 655360;   // float [2][4096]
constexpr int SEL_F_OFF = 663552;   // int   [2][4096]
constexpr int SIV_F_OFF = 671744;   // float [2][4096] -> ends 679936
constexpr int WB_F_OFF  = 679936;   // bf16 weights (batch-0 only), 49152 f -> 729088 < CP

typedef __attribute__((ext_vector_type(8))) short short8;
typedef __attribute__((ext_vector_type(4))) float f32x4;

__device__ inline unsigned short bf16_rne(float f) {
    unsigned u = __float_as_uint(f);
    return (unsigned short)((u + 0x7fffu + ((u >> 16) & 1u)) >> 16);
}
__device__ inline unsigned pack2(float a, float b) {
    return (unsigned)bf16_rne(a) | ((unsigned)bf16_rne(b) << 16);
}

// ---------------------------------------------------------------------------
// Kernel: convert conv weights fp32 -> bf16 (RNE), layout unchanged [m][k]
// ---------------------------------------------------------------------------
__global__ __launch_bounds__(256) void k_wcvt(const float* __restrict__ Wg,
                                              unsigned short* __restrict__ Wb) {
    int i = blockIdx.x * 256 + threadIdx.x;   // 196608 elems, grid exact
    Wb[i] = bf16_rne(Wg[i]);
}

// ---------------------------------------------------------------------------
// Kernel: fused neighbor-dots + sumsq (proven round 8: float4 staging +
// 4-way channel chunks). Block = 4-row strip (256 px) x 64-ch chunk; each
// channel's working set (cur 1KB + prev 1.5KB + next 1.5KB) = one float4
// per thread; LDS double-buffer, 2-deep register prefetch, one syncthreads
// per channel. Partials (18 dots + 2 sumsq, fp64) -> per-batch scratch;
// fixed chunk-sum order downstream => clipped-duplicate neighbors
// bit-identical => strict-< first-min tie-break preserved.
// ---------------------------------------------------------------------------
__global__ __launch_bounds__(256) void k_dots(const float* __restrict__ x,
                                              float* __restrict__ out) {
    __shared__ float ys[2][2][6][64];   // [buf][side][row][x] 6 KB
    __shared__ float cs[2][256];        // [buf][px]            2 KB
    const int t     = threadIdx.x;
    const int b     = blockIdx.x >> 4;
    const int strip = blockIdx.x & 15;
    const int chunk = blockIdx.y;       // 0..3 -> channels [64*chunk, +64)
    const int y0 = strip * 4;
    const int ry = t >> 6;              // own row in strip (0..3)
    const int xc = t & 63;
    const int xm = max(xc - 1, 0), xp = min(xc + 1, 63);
    const int c0 = chunk * 64;

    // one float4 staging slot per thread: 64 cur + 96 prev + 96 next = 256
    size_t gbase; int l0;               // LDS float offset (per buf)
    if (t < 64) {
        // cur strip: pixel offset strip*256 + t*4 (FLOAT units)
        gbase = (size_t)(b * 3 + 2) * CP + (size_t)c0 * P + strip * 256 + t * 4;
        l0 = t * 4;                     // cs slot
    } else {
        int i   = t - 64;               // 0..191
        int sid = i >= 96;              // 0=prev, 1=next
        int r   = (i - sid * 96) >> 4;  // staged row 0..5
        int x4  = i & 15;               // 96 = 6*16 -> (i-96)&15 == i&15
        int yl  = min(max(y0 - 1 + r, 0), Hh - 1);
        gbase = (size_t)(b * 3 + sid) * CP + (size_t)c0 * P + yl * 64 + x4 * 4;
        l0 = (sid * 6 + r) * 64 + x4 * 4;
    }
    float* ysf = &ys[0][0][0][0];       // flat view; buf stride = 768 floats
    float* dst0 = (t < 64) ? &cs[0][l0] : &ysf[l0];
    float* dst1 = (t < 64) ? &cs[1][l0] : &ysf[768 + l0];

    double d[2][9] = {{0,0,0,0,0,0,0,0,0},{0,0,0,0,0,0,0,0,0}};
    double qs[2] = {0.0, 0.0};

    f32x4 r0 = *(const f32x4*)(x + gbase);                  // chan 0
    f32x4 r1 = *(const f32x4*)(x + gbase + (size_t)P);      // chan 1

    #define COMPUTE(BUF)                                                     \
    {                                                                        \
        double cd = (double)cs[BUF][t];                                      \
        _Pragma("unroll")                                                    \
        for (int s = 0; s < 2; ++s) {                                        \
            const float* Y0 = &ys[BUF][s][ry][0];     /* own y - 1 */        \
            const float* Y1 = Y0 + 64;                /* own y     */        \
            const float* Y2 = Y1 + 64;                /* own y + 1 */        \
            d[s][0] = fma(cd, (double)Y0[xm], d[s][0]);                      \
            d[s][1] = fma(cd, (double)Y0[xc], d[s][1]);                      \
            d[s][2] = fma(cd, (double)Y0[xp], d[s][2]);                      \
            d[s][3] = fma(cd, (double)Y1[xm], d[s][3]);                      \
            d[s][4] = fma(cd, (double)Y1[xc], d[s][4]);                      \
            d[s][5] = fma(cd, (double)Y1[xp], d[s][5]);                      \
            d[s][6] = fma(cd, (double)Y2[xm], d[s][6]);                      \
            d[s][7] = fma(cd, (double)Y2[xc], d[s][7]);                      \
            d[s][8] = fma(cd, (double)Y2[xp], d[s][8]);                      \
            double ov = (double)Y1[xc];                                      \
            qs[s] = fma(ov, ov, qs[s]);                                      \
        }                                                                    \
    }

    for (int n = 0; n < 64; n += 2) {
        *(f32x4*)dst0 = r0;                 // chan n   -> buf0 (waits r0)
        __syncthreads();                    // buf0 visible; compute(n-2) done
        if (n + 2 < 64)
            r0 = *(const f32x4*)(x + gbase + (size_t)(n + 2) * P);
        COMPUTE(0)                          // chan n
        *(f32x4*)dst1 = r1;                 // chan n+1 -> buf1 (waits r1)
        __syncthreads();                    // buf1 visible; compute(n-1) done
        if (n + 3 < 64)
            r1 = *(const f32x4*)(x + gbase + (size_t)(n + 3) * P);
        COMPUTE(1)                          // chan n+1
    }
    #undef COMPUTE

    const int p = strip * 256 + t;
    double* db = (double*)(out + (size_t)(b * 3) * CP);
    #pragma unroll
    for (int s = 0; s < 2; ++s) {
        #pragma unroll
        for (int k = 0; k < 9; ++k)
            db[DOT_D_OFF + (size_t)((chunk * 2 + s) * 9 + k) * 4096 + p] = d[s][k];
        db[SSQ_D_OFF + (size_t)(chunk * 2 + s) * 4096 + p] = qs[s];
    }
}

// ---------------------------------------------------------------------------
// Kernel: inv L2 norms from sumsq partials (fixed chunk-order fp64 sum)
// ---------------------------------------------------------------------------
__global__ __launch_bounds__(256) void k_iv(float* __restrict__ out) {
    int gid  = blockIdx.x * 256 + threadIdx.x;   // 0..65535
    int side = gid >> 15;
    int j    = gid & (J - 1);
    int b = j >> 12, p = j & (P - 1);
    const double* sb = (const double*)(out + (size_t)(b * 3) * CP) + SSQ_D_OFF;
    double ssum = ((sb[(0 * 2 + side) * 4096 + p]
                  + sb[(1 * 2 + side) * 4096 + p])
                  + sb[(2 * 2 + side) * 4096 + p])
                  + sb[(3 * 2 + side) * 4096 + p];
    float* ivb = out + (size_t)(b * 3) * CP + IV_F_OFF;
    ivb[side * 4096 + p] = 1.0f / fmaxf((float)sqrt(ssum), 1e-12f);
}

// ---------------------------------------------------------------------------
// Kernel: final argmin over 9 neighbors (fixed chunk-order fp64 sum;
// duplicates bit-identical; strict < = first-min tie-break)
// ---------------------------------------------------------------------------
__global__ __launch_bounds__(256) void k_sel(float* __restrict__ out) {
    int gid  = blockIdx.x * 256 + threadIdx.x;
    int side = gid >> 15;
    int j    = gid & (J - 1);
    int b = j >> 12, p = j & (P - 1);
    int y = p >> 6, xc = p & 63;

    int nidx[9];
    #pragma unroll
    for (int k = 0; k < 9; ++k) {
        int dy = k / 3 - 1, dx = k % 3 - 1;     // y_off=repeat, x_off=tile
        int yy = min(max(y + dy, 0), Hh - 1);
        int xx = min(max(xc + dx, 0), Ww - 1);
        nidx[k] = yy * Ww + xx;
    }

    const double* db  = (const double*)(out + (size_t)(b * 3) * CP) + DOT_D_OFF;
    const float*  ivb = out + (size_t)(b * 3) * CP + IV_F_OFF;

    double best = 0.0; int bi = 0;
    #pragma unroll
    for (int k = 0; k < 9; ++k) {
        double sk = ((db[(size_t)((0 * 2 + side) * 9 + k) * 4096 + p]
                    + db[(size_t)((1 * 2 + side) * 9 + k) * 4096 + p])
                    + db[(size_t)((2 * 2 + side) * 9 + k) * 4096 + p])
                    + db[(size_t)((3 * 2 + side) * 9 + k) * 4096 + p];
        double s = sk * (double)ivb[side * 4096 + nidx[k]];
        if (k == 0 || s < best) { best = s; bi = k; }
    }
    int*   selb = (int*)(out + (size_t)(b * 3) * CP + SEL_F_OFF);
    float* sivb = out + (size_t)(b * 3) * CP + SIV_F_OFF;
    selb[side * 4096 + p] = nidx[bi];
    sivb[side * 4096 + p] = ivb[side * 4096 + nidx[bi]];
}

// ---------------------------------------------------------------------------
// Kernel: bf16 MFMA GEMM, SOFTWARE-PIPELINED (round 9). C[m=256][jtile=128]
// = sum_k W[m][k]*F(k,j), K=768, 24 steps of 32. Old loop exposed ~600cyc
// load latency per step (loads issued after prior MFMA; grid 256 = 1
// block/CU, 8 lockstep waves). New loop: double-buffered LDS (As/Bs x2,
// 48KB); per iter: issue loads(i+1) -> MFMA(i) from buf[i&1] -> write
// buf[(i+1)&1] -> one barrier. Write-after-read safe: any wave's write to
// buf[(i+1)&1] is past barrier(i-1), which requires all waves to have
// finished compute(i-1) (that buffer's last readers). Numerics identical.
// ---------------------------------------------------------------------------
__global__ __launch_bounds__(512) void k_gemm(const float* __restrict__ x,
                                              const unsigned short* __restrict__ Wb,
                                              float* __restrict__ out) {
    __shared__ unsigned short As[2][4][256][8];   // 32 KB, k-octet blocked
    __shared__ unsigned short Bs[2][4][128][8];   // 16 KB
    __shared__ int   sel_s[2][128];
    __shared__ float siv_s[2][128];

    const int t  = threadIdx.x;
    const int j0 = blockIdx.x * 128;
    const int b  = j0 >> 12, p0 = j0 & (P - 1);   // 128 | 4096 -> b uniform

    if (t < 256) {
        int side = t >> 7, jj = t & 127;
        const int*   selb = (const int*)(out + (size_t)(b * 3) * CP + SEL_F_OFF);
        const float* sivb = out + (size_t)(b * 3) * CP + SIV_F_OFF;
        sel_s[side][jj] = selb[side * 4096 + p0 + jj];
        siv_s[side][jj] = sivb[side * 4096 + p0 + jj];
    }
    __syncthreads();

    const int lane = t & 63, w = t >> 6;
    const int q = lane >> 4, l16 = lane & 15;
    const int m0w = (w & 3) * 64;      // 4 m-quadrants of 256
    const int n0w = (w >> 2) * 64;     // 2 n-halves of 128

    const int jj = t & 127, kq = (t >> 7) & 3;   // B staging role
    const int ma = t & 255, kh = t >> 8;         // A staging role
    const int k0 = kq * 8;

    // hoisted gather bases + scales (sel/siv LDS reads off the hot loop)
    const float* pp = x + (size_t)(b * 3 + 0) * CP + sel_s[0][jj];
    const float* np = x + (size_t)(b * 3 + 1) * CP + sel_s[1][jj];
    const float* cp = x + (size_t)(b * 3 + 2) * CP + p0 + jj;
    const float  sp = siv_s[0][jj], sn = siv_s[1][jj];
    const unsigned short* wbase = Wb + (size_t)ma * CT + kh * 16;

    f32x4 acc[4][4];
    #pragma unroll
    for (int f = 0; f < 4; ++f)
        #pragma unroll
        for (int g = 0; g < 4; ++g)
            acc[f][g] = (f32x4){0.f, 0.f, 0.f, 0.f};

    short8 wa0, wa1;
    float fb[8];
    float scale;

    #define LOAD_STEP(KK)                                                    \
    {                                                                        \
        const unsigned short* wsrc = wbase + (KK);                           \
        wa0 = *(const short8*)wsrc;                                          \
        wa1 = *(const short8*)(wsrc + 8);                                    \
        const float* src;                                                    \
        if ((KK) < 256)      { src = pp + (size_t)((KK) + k0) * P;       scale = sp;   } \
        else if ((KK) < 512) { src = np + (size_t)((KK) - 256 + k0) * P; scale = sn;   } \
        else                 { src = cp + (size_t)((KK) - 512 + k0) * P; scale = 1.0f; } \
        _Pragma("unroll")                                                    \
        for (int u = 0; u < 8; ++u) fb[u] = src[(size_t)u * P];              \
    }

    #define WRITE_STEP(BUF)                                                  \
    {                                                                        \
        *(short8*)&As[BUF][kh * 2    ][ma][0] = wa0;                         \
        *(short8*)&As[BUF][kh * 2 + 1][ma][0] = wa1;                         \
        uint4 pk = make_uint4(pack2(fb[0] * scale, fb[1] * scale),           \
                              pack2(fb[2] * scale, fb[3] * scale),           \
                              pack2(fb[4] * scale, fb[5] * scale),           \
                              pack2(fb[6] * scale, fb[7] * scale));          \
        *(uint4*)&Bs[BUF][kq][jj][0] = pk;                                   \
    }

    LOAD_STEP(0)
    WRITE_STEP(0)
    __syncthreads();

    for (int i = 0; i < 24; ++i) {
        if (i + 1 < 24) LOAD_STEP((i + 1) * 32)       // in flight during MFMA
        const int cur = i & 1;
        short8 af[4], bfr[4];
        #pragma unroll
        for (int f = 0; f < 4; ++f)
            af[f] = *(const short8*)&As[cur][q][m0w + f * 16 + l16][0];
        #pragma unroll
        for (int g = 0; g < 4; ++g)
            bfr[g] = *(const short8*)&Bs[cur][q][n0w + g * 16 + l16][0];
        #pragma unroll
        for (int f = 0; f < 4; ++f)
            #pragma unroll
            for (int g = 0; g < 4; ++g)
                acc[f][g] = __builtin_amdgcn_mfma_f32_16x16x32_bf16(
                    af[f], bfr[g], acc[f][g], 0, 0, 0);
        if (i + 1 < 24) WRITE_STEP((i + 1) & 1)
        __syncthreads();
    }
    #undef LOAD_STEP
    #undef WRITE_STEP

    // epilogue: D[row=q*4+r][col=l16] per 16x16 frag (measured C/D layout)
    float* outb = out + (size_t)(b * 3 + 2) * CP;
    #pragma unroll
    for (int f = 0; f < 4; ++f)
        #pragma unroll
        for (int g = 0; g < 4; ++g)
            #pragma unroll
            for (int r = 0; r < 4; ++r) {
                int ch  = m0w + f * 16 + q * 4 + r;
                int col = p0 + n0w + g * 16 + l16;
                outb[(size_t)ch * P + col] = acc[f][g][r];
            }
}

// ---------------------------------------------------------------------------
// Kernel: per-channel BN stats + normalize + ReLU in place on out slot 2
// ---------------------------------------------------------------------------
__global__ __launch_bounds__(256) void k_bn(float* __restrict__ out,
                                            const float* __restrict__ gamma,
                                            const float* __restrict__ beta) {
    __shared__ double rs[256], rq[256];
    __shared__ float sc_s, sh_s;
    const int o = blockIdx.x, t = threadIdx.x;

    double s = 0.0, q = 0.0;
    for (int b = 0; b < B; ++b) {
        const float4* base =
            (const float4*)(out + (size_t)(b * 3 + 2) * CP + (size_t)o * P);
        #pragma unroll
        for (int i = 0; i < 4; ++i) {
            float4 v = base[i * 256 + t];
            s += (double)v.x + (double)v.y + (double)v.z + (double)v.w;
            q += (double)v.x * v.x + (double)v.y * v.y
               + (double)v.z * v.z + (double)v.w * v.w;
        }
    }
    rs[t] = s; rq[t] = q;
    __syncthreads();
    for (int off = 128; off > 0; off >>= 1) {
        if (t < off) { rs[t] += rs[t + off]; rq[t] += rq[t + off]; }
        __syncthreads();
    }
    if (t == 0) {
        double mean = rs[0] * (1.0 / (double)J);
        double var  = rq[0] * (1.0 / (double)J) - mean * mean;
        double inv  = 1.0 / sqrt(var + 1e-5);
        double sc   = (double)gamma[o] * inv;
        sc_s = (float)sc;
        sh_s = (float)((double)beta[o] - mean * sc);
    }
    __syncthreads();
    const float sc = sc_s, sh = sh_s;

    for (int b = 0; b < B; ++b) {
        float4* base =
            (float4*)(out + (size_t)(b * 3 + 2) * CP + (size_t)o * P);
        #pragma unroll
        for (int i = 0; i < 4; ++i) {
            float4 v = base[i * 256 + t];
            v.x = fmaxf(fmaf(v.x, sc, sh), 0.f);
            v.y = fmaxf(fmaf(v.y, sc, sh), 0.f);
            v.z = fmaxf(fmaf(v.z, sc, sh), 0.f);
            v.w = fmaxf(fmaf(v.w, sc, sh), 0.f);
            base[i * 256 + t] = v;
        }
    }
}

// ---------------------------------------------------------------------------
// Kernel: copy prev/next slices to output slots 0/1 (runs LAST: overwrites
// the scratch region used by earlier kernels)
// ---------------------------------------------------------------------------
__global__ __launch_bounds__(256) void k_copy(const float4* __restrict__ x4,
                                              float4* __restrict__ o4) {
    int tid = blockIdx.x * blockDim.x + threadIdx.x;
    const int per_b = 2 * CP / 4;
    const int bstr  = 3 * CP / 4;
    if (tid < B * per_b) {
        int b = tid / per_b;
        int r = tid - b * per_b;
        o4[b * bstr + r] = x4[b * bstr + r];
    }
}

// ---------------------------------------------------------------------------
extern "C" void kernel_launch(void* const* d_in, const int* in_sizes, int n_in,
                              void* d_out, int out_size, void* d_ws, size_t ws_size,
                              hipStream_t stream) {
    const float* x     = (const float*)d_in[0];
    const float* wconv = (const float*)d_in[1];
    const float* gamma = (const float*)d_in[2];
    const float* beta  = (const float*)d_in[3];
    float* out = (float*)d_out;
    (void)d_ws; (void)ws_size;   // deliberately unused

    unsigned short* Wbuf = (unsigned short*)(out + WB_F_OFF);

    k_wcvt<<<CT * C / 256, 256, 0, stream>>>(wconv, Wbuf);

    // fused dots+sumsq: (8 batches x 16 strips) x 4 channel chunks
    k_dots<<<dim3(128, 4), 256, 0, stream>>>(x, out);

    k_iv<<<2 * J / 256, 256, 0, stream>>>(out);

    k_sel<<<2 * J / 256, 256, 0, stream>>>(out);

    k_gemm<<<J / 128, 512, 0, stream>>>(x, Wbuf, out);

    k_bn<<<C, 256, 0, stream>>>(out, gamma, beta);

    k_copy<<<(B * 2 * CP / 4 + 255) / 256, 256, 0, stream>>>(
        (const float4*)x, (float4*)out);
}

// Round 11
// 262.047 us; speedup vs baseline: 1.5217x; 1.0208x over previous
//
#include <hip/hip_runtime.h>

// Problem constants
constexpr int B  = 8;
constexpr int C  = 256;
constexpr int Hh = 64;
constexpr int Ww = 64;
constexpr int P  = Hh * Ww;        // 4096 pixels
constexpr int CP = C * P;          // elements per (b,t) slice
constexpr int CT = 3 * C;          // 768 concat channels
constexpr int J  = B * P;          // 32768 columns

// Per-batch scratch inside out slot-0 of batch b (4-chunk layout).
// DOT/SSQ offsets in DOUBLES from slot-0 base; SEL/SIV/WB in floats.
// k_copy overwrites slots 0/1 LAST; gemm writes slot 2 only -> no overlap.
constexpr int DOT_D_OFF = 0;        // double[4][2][9][4096] (chunk,side,k,p) = 294912 d
constexpr int SSQ_D_OFF = 294912;   // double[4][2][4096]    (chunk,side,p)   = 32768 d
constexpr int SEL_F_OFF = 663552;   // int   [2][4096]
constexpr int SIV_F_OFF = 671744;   // float [2][4096] -> ends 679936
constexpr int WB_F_OFF  = 679936;   // bf16 weights (batch-0 only), 49152 f -> 729088 < CP

typedef __attribute__((ext_vector_type(8))) short short8;
typedef __attribute__((ext_vector_type(4))) float f32x4;

__device__ inline unsigned short bf16_rne(float f) {
    unsigned u = __float_as_uint(f);
    return (unsigned short)((u + 0x7fffu + ((u >> 16) & 1u)) >> 16);
}
__device__ inline unsigned pack2(float a, float b) {
    return (unsigned)bf16_rne(a) | ((unsigned)bf16_rne(b) << 16);
}

// ---------------------------------------------------------------------------
// Kernel: convert conv weights fp32 -> bf16 (RNE), layout unchanged [m][k]
// ---------------------------------------------------------------------------
__global__ __launch_bounds__(256) void k_wcvt(const float* __restrict__ Wg,
                                              unsigned short* __restrict__ Wb) {
    int i = blockIdx.x * 256 + threadIdx.x;   // 196608 elems, grid exact
    Wb[i] = bf16_rne(Wg[i]);
}

// ---------------------------------------------------------------------------
// Kernel: fused neighbor-dots + sumsq. Round-11: TWO channels staged per
// LDS phase (each thread issues 2 float4 loads/phase; 4 in flight with the
// double buffer) -> in-flight bytes/CU doubled vs round 8 (the limiter
// measured in r7->r8: 77->~45us when blocks/CU doubled); barrier count
// halved (32/block). Block = 4-row strip (256 px) x 64-ch chunk; per
// channel, working set = cur 1KB + prev 1.5KB + next 1.5KB = one float4
// per thread. Per-thread accumulation stays ascending-channel => partials
// BIT-IDENTICAL to round 8. Partials (18 dots + 2 sumsq fp64) -> per-batch
// scratch; fixed chunk order downstream => strict-< tie-break preserved.
// ---------------------------------------------------------------------------
__global__ __launch_bounds__(256) void k_dots(const float* __restrict__ x,
                                              float* __restrict__ out) {
    __shared__ float ys[2][2][2][6][64];  // [buf][ch][side][row][x] 12 KB
    __shared__ float cs[2][2][256];       // [buf][ch][px]            4 KB
    const int t     = threadIdx.x;
    const int b     = blockIdx.x >> 4;
    const int strip = blockIdx.x & 15;
    const int chunk = blockIdx.y;       // 0..3 -> channels [64*chunk, +64)
    const int y0 = strip * 4;
    const int ry = t >> 6;              // own row in strip (0..3)
    const int xc = t & 63;
    const int xm = max(xc - 1, 0), xp = min(xc + 1, 63);
    const int c0 = chunk * 64;

    // one float4 staging slot per thread per channel:
    // 64 cur + 96 prev + 96 next = 256 slots
    size_t gbase;
    float *d00, *d01, *d10, *d11;       // [buf][ch-in-pair] destinations
    float* ysf = &ys[0][0][0][0][0];    // strides: buf 1536, ch 768
    float* csf = &cs[0][0][0];          // strides: buf 512,  ch 256
    if (t < 64) {
        gbase = (size_t)(b * 3 + 2) * CP + (size_t)c0 * P + strip * 256 + t * 4;
        int l0 = t * 4;
        d00 = csf + l0;        d01 = csf + 256 + l0;
        d10 = csf + 512 + l0;  d11 = csf + 768 + l0;
    } else {
        int i   = t - 64;               // 0..191
        int sid = i >= 96;              // 0=prev, 1=next
        int r   = (i - sid * 96) >> 4;  // staged row 0..5
        int x4  = i & 15;
        int yl  = min(max(y0 - 1 + r, 0), Hh - 1);
        gbase = (size_t)(b * 3 + sid) * CP + (size_t)c0 * P + yl * 64 + x4 * 4;
        int l0 = (sid * 6 + r) * 64 + x4 * 4;      // 0..767
        d00 = ysf + l0;         d01 = ysf + 768 + l0;
        d10 = ysf + 1536 + l0;  d11 = ysf + 1536 + 768 + l0;
    }

    double d[2][9] = {{0,0,0,0,0,0,0,0,0},{0,0,0,0,0,0,0,0,0}};
    double qs[2] = {0.0, 0.0};

    f32x4 a0 = *(const f32x4*)(x + gbase);                      // chan 0
    f32x4 a1 = *(const f32x4*)(x + gbase + (size_t)P);          // chan 1
    f32x4 b0 = *(const f32x4*)(x + gbase + (size_t)2 * P);      // chan 2
    f32x4 b1 = *(const f32x4*)(x + gbase + (size_t)3 * P);      // chan 3

    #define COMPUTE(BUF, CH)                                                 \
    {                                                                        \
        double cd = (double)cs[BUF][CH][t];                                  \
        _Pragma("unroll")                                                    \
        for (int s = 0; s < 2; ++s) {                                        \
            const float* Y0 = &ys[BUF][CH][s][ry][0];   /* own y - 1 */      \
            const float* Y1 = Y0 + 64;                  /* own y     */      \
            const float* Y2 = Y1 + 64;                  /* own y + 1 */      \
            d[s][0] = fma(cd, (double)Y0[xm], d[s][0]);                      \
            d[s][1] = fma(cd, (double)Y0[xc], d[s][1]);                      \
            d[s][2] = fma(cd, (double)Y0[xp], d[s][2]);                      \
            d[s][3] = fma(cd, (double)Y1[xm], d[s][3]);                      \
            d[s][4] = fma(cd, (double)Y1[xc], d[s][4]);                      \
            d[s][5] = fma(cd, (double)Y1[xp], d[s][5]);                      \
            d[s][6] = fma(cd, (double)Y2[xm], d[s][6]);                      \
            d[s][7] = fma(cd, (double)Y2[xc], d[s][7]);                      \
            d[s][8] = fma(cd, (double)Y2[xp], d[s][8]);                      \
            double ov = (double)Y1[xc];                                      \
            qs[s] = fma(ov, ov, qs[s]);                                      \
        }                                                                    \
    }

    for (int n = 0; n < 64; n += 4) {
        *(f32x4*)d00 = a0; *(f32x4*)d01 = a1;   // chans n, n+1 -> buf0
        __syncthreads();      // buf0 visible; all waves past COMPUTE(0,*) of
                              // prev iter via its mid-iter barrier
        if (n + 4 < 64) {
            a0 = *(const f32x4*)(x + gbase + (size_t)(n + 4) * P);
            a1 = *(const f32x4*)(x + gbase + (size_t)(n + 5) * P);
        }
        COMPUTE(0, 0) COMPUTE(0, 1)             // chans n, n+1
        *(f32x4*)d10 = b0; *(f32x4*)d11 = b1;   // chans n+2, n+3 -> buf1
        __syncthreads();
        if (n + 6 < 64) {
            b0 = *(const f32x4*)(x + gbase + (size_t)(n + 6) * P);
            b1 = *(const f32x4*)(x + gbase + (size_t)(n + 7) * P);
        }
        COMPUTE(1, 0) COMPUTE(1, 1)             // chans n+2, n+3
    }
    #undef COMPUTE

    const int p = strip * 256 + t;
    double* db = (double*)(out + (size_t)(b * 3) * CP);
    #pragma unroll
    for (int s = 0; s < 2; ++s) {
        #pragma unroll
        for (int k = 0; k < 9; ++k)
            db[DOT_D_OFF + (size_t)((chunk * 2 + s) * 9 + k) * 4096 + p] = d[s][k];
        db[SSQ_D_OFF + (size_t)(chunk * 2 + s) * 4096 + p] = qs[s];
    }
}

// ---------------------------------------------------------------------------
// Kernel: final argmin over 9 neighbors, with inv-norm FUSED (round 11:
// absorbs old k_iv — each neighbor's iv recomputed from SSQ partials with
// the exact same float expression => bit-identical siv; saves one launch
// and one pass). Fixed chunk-order fp64 sums; duplicates bit-identical;
// strict < = first-min tie-break.
// ---------------------------------------------------------------------------
__global__ __launch_bounds__(256) void k_sel(float* __restrict__ out) {
    int gid  = blockIdx.x * 256 + threadIdx.x;
    int side = gid >> 15;
    int j    = gid & (J - 1);
    int b = j >> 12, p = j & (P - 1);
    int y = p >> 6, xc = p & 63;

    int nidx[9];
    #pragma unroll
    for (int k = 0; k < 9; ++k) {
        int dy = k / 3 - 1, dx = k % 3 - 1;     // y_off=repeat, x_off=tile
        int yy = min(max(y + dy, 0), Hh - 1);
        int xx = min(max(xc + dx, 0), Ww - 1);
        nidx[k] = yy * Ww + xx;
    }

    const double* db = (const double*)(out + (size_t)(b * 3) * CP) + DOT_D_OFF;
    const double* sb = (const double*)(out + (size_t)(b * 3) * CP) + SSQ_D_OFF;

    double best = 0.0; int bi = 0; float sivbest = 0.0f;
    #pragma unroll
    for (int k = 0; k < 9; ++k) {
        int nq = nidx[k];
        // inv L2 norm of neighbor position (identical expression to old k_iv)
        double ssum = ((sb[(0 * 2 + side) * 4096 + nq]
                      + sb[(1 * 2 + side) * 4096 + nq])
                      + sb[(2 * 2 + side) * 4096 + nq])
                      + sb[(3 * 2 + side) * 4096 + nq];
        float ivf = 1.0f / fmaxf((float)sqrt(ssum), 1e-12f);
        double sk = ((db[(size_t)((0 * 2 + side) * 9 + k) * 4096 + p]
                    + db[(size_t)((1 * 2 + side) * 9 + k) * 4096 + p])
                    + db[(size_t)((2 * 2 + side) * 9 + k) * 4096 + p])
                    + db[(size_t)((3 * 2 + side) * 9 + k) * 4096 + p];
        double s = sk * (double)ivf;
        if (k == 0 || s < best) { best = s; bi = k; sivbest = ivf; }
    }
    int*   selb = (int*)(out + (size_t)(b * 3) * CP + SEL_F_OFF);
    float* sivb = out + (size_t)(b * 3) * CP + SIV_F_OFF;
    selb[side * 4096 + p] = nidx[bi];
    sivb[side * 4096 + p] = sivbest;
}

// ---------------------------------------------------------------------------
// Kernel: bf16 MFMA GEMM, software-pipelined (round 9; perf-neutral vs r8
// but structurally cleaner). C[m=256][jtile=128] = sum_k W[m][k]*F(k,j),
// K=768, 24 steps of 32; double-buffered LDS; per iter: issue loads(i+1)
// -> MFMA(i) from buf[i&1] -> write buf[(i+1)&1] -> one barrier.
// ---------------------------------------------------------------------------
__global__ __launch_bounds__(512) void k_gemm(const float* __restrict__ x,
                                              const unsigned short* __restrict__ Wb,
                                              float* __restrict__ out) {
    __shared__ unsigned short As[2][4][256][8];   // 32 KB, k-octet blocked
    __shared__ unsigned short Bs[2][4][128][8];   // 16 KB
    __shared__ int   sel_s[2][128];
    __shared__ float siv_s[2][128];

    const int t  = threadIdx.x;
    const int j0 = blockIdx.x * 128;
    const int b  = j0 >> 12, p0 = j0 & (P - 1);   // 128 | 4096 -> b uniform

    if (t < 256) {
        int side = t >> 7, jj = t & 127;
        const int*   selb = (const int*)(out + (size_t)(b * 3) * CP + SEL_F_OFF);
        const float* sivb = out + (size_t)(b * 3) * CP + SIV_F_OFF;
        sel_s[side][jj] = selb[side * 4096 + p0 + jj];
        siv_s[side][jj] = sivb[side * 4096 + p0 + jj];
    }
    __syncthreads();

    const int lane = t & 63, w = t >> 6;
    const int q = lane >> 4, l16 = lane & 15;
    const int m0w = (w & 3) * 64;      // 4 m-quadrants of 256
    const int n0w = (w >> 2) * 64;     // 2 n-halves of 128

    const int jj = t & 127, kq = (t >> 7) & 3;   // B staging role
    const int ma = t & 255, kh = t >> 8;         // A staging role
    const int k0 = kq * 8;

    // hoisted gather bases + scales (sel/siv LDS reads off the hot loop)
    const float* pp = x + (size_t)(b * 3 + 0) * CP + sel_s[0][jj];
    const float* np = x + (size_t)(b * 3 + 1) * CP + sel_s[1][jj];
    const float* cp = x + (size_t)(b * 3 + 2) * CP + p0 + jj;
    const float  sp = siv_s[0][jj], sn = siv_s[1][jj];
    const unsigned short* wbase = Wb + (size_t)ma * CT + kh * 16;

    f32x4 acc[4][4];
    #pragma unroll
    for (int f = 0; f < 4; ++f)
        #pragma unroll
        for (int g = 0; g < 4; ++g)
            acc[f][g] = (f32x4){0.f, 0.f, 0.f, 0.f};

    short8 wa0, wa1;
    float fb[8];
    float scale;

    #define LOAD_STEP(KK)                                                    \
    {                                                                        \
        const unsigned short* wsrc = wbase + (KK);                           \
        wa0 = *(const short8*)wsrc;                                          \
        wa1 = *(const short8*)(wsrc + 8);                                    \
        const float* src;                                                    \
        if ((KK) < 256)      { src = pp + (size_t)((KK) + k0) * P;       scale = sp;   } \
        else if ((KK) < 512) { src = np + (size_t)((KK) - 256 + k0) * P; scale = sn;   } \
        else                 { src = cp + (size_t)((KK) - 512 + k0) * P; scale = 1.0f; } \
        _Pragma("unroll")                                                    \
        for (int u = 0; u < 8; ++u) fb[u] = src[(size_t)u * P];              \
    }

    #define WRITE_STEP(BUF)                                                  \
    {                                                                        \
        *(short8*)&As[BUF][kh * 2    ][ma][0] = wa0;                         \
        *(short8*)&As[BUF][kh * 2 + 1][ma][0] = wa1;                         \
        uint4 pk = make_uint4(pack2(fb[0] * scale, fb[1] * scale),           \
                              pack2(fb[2] * scale, fb[3] * scale),           \
                              pack2(fb[4] * scale, fb[5] * scale),           \
                              pack2(fb[6] * scale, fb[7] * scale));          \
        *(uint4*)&Bs[BUF][kq][jj][0] = pk;                                   \
    }

    LOAD_STEP(0)
    WRITE_STEP(0)
    __syncthreads();

    for (int i = 0; i < 24; ++i) {
        if (i + 1 < 24) LOAD_STEP((i + 1) * 32)       // in flight during MFMA
        const int cur = i & 1;
        short8 af[4], bfr[4];
        #pragma unroll
        for (int f = 0; f < 4; ++f)
            af[f] = *(const short8*)&As[cur][q][m0w + f * 16 + l16][0];
        #pragma unroll
        for (int g = 0; g < 4; ++g)
            bfr[g] = *(const short8*)&Bs[cur][q][n0w + g * 16 + l16][0];
        #pragma unroll
        for (int f = 0; f < 4; ++f)
            #pragma unroll
            for (int g = 0; g < 4; ++g)
                acc[f][g] = __builtin_amdgcn_mfma_f32_16x16x32_bf16(
                    af[f], bfr[g], acc[f][g], 0, 0, 0);
        if (i + 1 < 24) WRITE_STEP((i + 1) & 1)
        __syncthreads();
    }
    #undef LOAD_STEP
    #undef WRITE_STEP

    // epilogue: D[row=q*4+r][col=l16] per 16x16 frag (measured C/D layout)
    float* outb = out + (size_t)(b * 3 + 2) * CP;
    #pragma unroll
    for (int f = 0; f < 4; ++f)
        #pragma unroll
        for (int g = 0; g < 4; ++g)
            #pragma unroll
            for (int r = 0; r < 4; ++r) {
                int ch  = m0w + f * 16 + q * 4 + r;
                int col = p0 + n0w + g * 16 + l16;
                outb[(size_t)ch * P + col] = acc[f][g][r];
            }
}

// ---------------------------------------------------------------------------
// Kernel: per-channel BN stats + normalize + ReLU in place on out slot 2
// ---------------------------------------------------------------------------
__global__ __launch_bounds__(256) void k_bn(float* __restrict__ out,
                                            const float* __restrict__ gamma,
                                            const float* __restrict__ beta) {
    __shared__ double rs[256], rq[256];
    __shared__ float sc_s, sh_s;
    const int o = blockIdx.x, t = threadIdx.x;

    double s = 0.0, q = 0.0;
    for (int b = 0; b < B; ++b) {
        const float4* base =
            (const float4*)(out + (size_t)(b * 3 + 2) * CP + (size_t)o * P);
        #pragma unroll
        for (int i = 0; i < 4; ++i) {
            float4 v = base[i * 256 + t];
            s += (double)v.x + (double)v.y + (double)v.z + (double)v.w;
            q += (double)v.x * v.x + (double)v.y * v.y
               + (double)v.z * v.z + (double)v.w * v.w;
        }
    }
    rs[t] = s; rq[t] = q;
    __syncthreads();
    for (int off = 128; off > 0; off >>= 1) {
        if (t < off) { rs[t] += rs[t + off]; rq[t] += rq[t + off]; }
        __syncthreads();
    }
    if (t == 0) {
        double mean = rs[0] * (1.0 / (double)J);
        double var  = rq[0] * (1.0 / (double)J) - mean * mean;
        double inv  = 1.0 / sqrt(var + 1e-5);
        double sc   = (double)gamma[o] * inv;
        sc_s = (float)sc;
        sh_s = (float)((double)beta[o] - mean * sc);
    }
    __syncthreads();
    const float sc = sc_s, sh = sh_s;

    for (int b = 0; b < B; ++b) {
        float4* base =
            (float4*)(out + (size_t)(b * 3 + 2) * CP + (size_t)o * P);
        #pragma unroll
        for (int i = 0; i < 4; ++i) {
            float4 v = base[i * 256 + t];
            v.x = fmaxf(fmaf(v.x, sc, sh), 0.f);
            v.y = fmaxf(fmaf(v.y, sc, sh), 0.f);
            v.z = fmaxf(fmaf(v.z, sc, sh), 0.f);
            v.w = fmaxf(fmaf(v.w, sc, sh), 0.f);
            base[i * 256 + t] = v;
        }
    }
}

// ---------------------------------------------------------------------------
// Kernel: copy prev/next slices to output slots 0/1 (runs LAST: overwrites
// the scratch region used by earlier kernels)
// ---------------------------------------------------------------------------
__global__ __launch_bounds__(256) void k_copy(const float4* __restrict__ x4,
                                              float4* __restrict__ o4) {
    int tid = blockIdx.x * blockDim.x + threadIdx.x;
    const int per_b = 2 * CP / 4;
    const int bstr  = 3 * CP / 4;
    if (tid < B * per_b) {
        int b = tid / per_b;
        int r = tid - b * per_b;
        o4[b * bstr + r] = x4[b * bstr + r];
    }
}

// ---------------------------------------------------------------------------
extern "C" void kernel_launch(void* const* d_in, const int* in_sizes, int n_in,
                              void* d_out, int out_size, void* d_ws, size_t ws_size,
                              hipStream_t stream) {
    const float* x     = (const float*)d_in[0];
    const float* wconv = (const float*)d_in[1];
    const float* gamma = (const float*)d_in[2];
    const float* beta  = (const float*)d_in[3];
    float* out = (float*)d_out;
    (void)d_ws; (void)ws_size;   // deliberately unused

    unsigned short* Wbuf = (unsigned short*)(out + WB_F_OFF);

    k_wcvt<<<CT * C / 256, 256, 0, stream>>>(wconv, Wbuf);

    // fused dots+sumsq: (8 batches x 16 strips) x 4 channel chunks
    k_dots<<<dim3(128, 4), 256, 0, stream>>>(x, out);

    // argmin with fused inv-norm (absorbs old k_iv)
    k_sel<<<2 * J / 256, 256, 0, stream>>>(out);

    k_gemm<<<J / 128, 512, 0, stream>>>(x, Wbuf, out);

    k_bn<<<C, 256, 0, stream>>>(out, gamma, beta);

    k_copy<<<(B * 2 * CP / 4 + 255) / 256, 256, 0, stream>>>(
        (const float4*)x, (float4*)out);
}

// Round 13
// 257.310 us; speedup vs baseline: 1.5497x; 1.0184x over previous
//
#include <hip/hip_runtime.h>

// Problem constants
constexpr int B  = 8;
constexpr int C  = 256;
constexpr int Hh = 64;
constexpr int Ww = 64;
constexpr int P  = Hh * Ww;        // 4096 pixels
constexpr int CP = C * P;          // elements per (b,t) slice
constexpr int CT = 3 * C;          // 768 concat channels
constexpr int J  = B * P;          // 32768 columns

// Per-batch scratch inside out slot-0 of batch b (4-chunk layout).
// DOT/SSQ/BNS offsets in DOUBLES from slot-0 base; SEL/SIV/WB in floats.
// k_copy overwrites slots 0/1 LAST; gemm writes slot 2 only -> no overlap.
// Batch-0 slot-0 additionally holds WB + BNS (disjoint from per-batch regions):
//   DOT  floats       0..655360   (294912 doubles)
//   SSQ  floats  589824..655360   (32768 doubles at d-off 294912)
//   SEL  floats  663552..667648
//   SIV  floats  671744..675840
//   WB   floats  679936..778240   (196608 u16 = 98304 floats — NOT 49152!
//                                  round-12 bug: BNS placed at 729088 sat
//                                  INSIDE Wb -> atomics corrupted W rows
//                                  128-130 + stats. Fixed below.)
//   BNS  floats  778240..779264   (512 doubles at d-off 389120)
constexpr int DOT_D_OFF = 0;        // double[4][2][9][4096] (chunk,side,k,p)
constexpr int SSQ_D_OFF = 294912;   // double[4][2][4096]    (chunk,side,p)
constexpr int SEL_F_OFF = 663552;   // int   [2][4096]
constexpr int SIV_F_OFF = 671744;   // float [2][4096]
constexpr int WB_F_OFF  = 679936;   // bf16 weights (batch-0 only)
constexpr int BNS_D_OFF = 389120;   // double[512]: sums[256], sumsq[256]

typedef __attribute__((ext_vector_type(8))) short short8;
typedef __attribute__((ext_vector_type(4))) float f32x4;

__device__ inline unsigned short bf16_rne(float f) {
    unsigned u = __float_as_uint(f);
    return (unsigned short)((u + 0x7fffu + ((u >> 16) & 1u)) >> 16);
}
__device__ inline unsigned pack2(float a, float b) {
    return (unsigned)bf16_rne(a) | ((unsigned)bf16_rne(b) << 16);
}

// ---------------------------------------------------------------------------
// Kernel: convert conv weights fp32 -> bf16 (RNE) + zero the BN-stats slab
// (runs first; gemm atomically accumulates into it; BNS now DISJOINT from Wb)
// ---------------------------------------------------------------------------
__global__ __launch_bounds__(256) void k_wcvt(const float* __restrict__ Wg,
                                              unsigned short* __restrict__ Wb,
                                              float* __restrict__ out) {
    int i = blockIdx.x * 256 + threadIdx.x;   // 196608 elems, grid exact
    Wb[i] = bf16_rne(Wg[i]);
    if (blockIdx.x == 0) {
        double* bns = (double*)out + BNS_D_OFF;
        bns[threadIdx.x]       = 0.0;
        bns[256 + threadIdx.x] = 0.0;
    }
}

// ---------------------------------------------------------------------------
// Kernel: fused neighbor-dots + sumsq (proven rounds 8/11). Block = 4-row
// strip (256 px) x 64-ch chunk; TWO channels staged per LDS phase (2 float4
// loads/thread/phase, 4 in flight); barrier count halved. Per-thread
// accumulation ascending-channel => partials bit-identical to round 8.
// Partials (18 dots + 2 sumsq fp64) -> per-batch scratch; fixed chunk order
// downstream => strict-< tie-break preserved.
// ---------------------------------------------------------------------------
__global__ __launch_bounds__(256) void k_dots(const float* __restrict__ x,
                                              float* __restrict__ out) {
    __shared__ float ys[2][2][2][6][64];  // [buf][ch][side][row][x] 12 KB
    __shared__ float cs[2][2][256];       // [buf][ch][px]            4 KB
    const int t     = threadIdx.x;
    const int b     = blockIdx.x >> 4;
    const int strip = blockIdx.x & 15;
    const int chunk = blockIdx.y;       // 0..3 -> channels [64*chunk, +64)
    const int y0 = strip * 4;
    const int ry = t >> 6;              // own row in strip (0..3)
    const int xc = t & 63;
    const int xm = max(xc - 1, 0), xp = min(xc + 1, 63);
    const int c0 = chunk * 64;

    // one float4 staging slot per thread per channel:
    // 64 cur + 96 prev + 96 next = 256 slots
    size_t gbase;
    float *d00, *d01, *d10, *d11;       // [buf][ch-in-pair] destinations
    float* ysf = &ys[0][0][0][0][0];    // strides: buf 1536, ch 768
    float* csf = &cs[0][0][0];          // strides: buf 512,  ch 256
    if (t < 64) {
        gbase = (size_t)(b * 3 + 2) * CP + (size_t)c0 * P + strip * 256 + t * 4;
        int l0 = t * 4;
        d00 = csf + l0;        d01 = csf + 256 + l0;
        d10 = csf + 512 + l0;  d11 = csf + 768 + l0;
    } else {
        int i   = t - 64;               // 0..191
        int sid = i >= 96;              // 0=prev, 1=next
        int r   = (i - sid * 96) >> 4;  // staged row 0..5
        int x4  = i & 15;
        int yl  = min(max(y0 - 1 + r, 0), Hh - 1);
        gbase = (size_t)(b * 3 + sid) * CP + (size_t)c0 * P + yl * 64 + x4 * 4;
        int l0 = (sid * 6 + r) * 64 + x4 * 4;      // 0..767
        d00 = ysf + l0;         d01 = ysf + 768 + l0;
        d10 = ysf + 1536 + l0;  d11 = ysf + 1536 + 768 + l0;
    }

    double d[2][9] = {{0,0,0,0,0,0,0,0,0},{0,0,0,0,0,0,0,0,0}};
    double qs[2] = {0.0, 0.0};

    f32x4 a0 = *(const f32x4*)(x + gbase);                      // chan 0
    f32x4 a1 = *(const f32x4*)(x + gbase + (size_t)P);          // chan 1
    f32x4 b0 = *(const f32x4*)(x + gbase + (size_t)2 * P);      // chan 2
    f32x4 b1 = *(const f32x4*)(x + gbase + (size_t)3 * P);      // chan 3

    #define COMPUTE(BUF, CH)                                                 \
    {                                                                        \
        double cd = (double)cs[BUF][CH][t];                                  \
        _Pragma("unroll")                                                    \
        for (int s = 0; s < 2; ++s) {                                        \
            const float* Y0 = &ys[BUF][CH][s][ry][0];   /* own y - 1 */      \
            const float* Y1 = Y0 + 64;                  /* own y     */      \
            const float* Y2 = Y1 + 64;                  /* own y + 1 */      \
            d[s][0] = fma(cd, (double)Y0[xm], d[s][0]);                      \
            d[s][1] = fma(cd, (double)Y0[xc], d[s][1]);                      \
            d[s][2] = fma(cd, (double)Y0[xp], d[s][2]);                      \
            d[s][3] = fma(cd, (double)Y1[xm], d[s][3]);                      \
            d[s][4] = fma(cd, (double)Y1[xc], d[s][4]);                      \
            d[s][5] = fma(cd, (double)Y1[xp], d[s][5]);                      \
            d[s][6] = fma(cd, (double)Y2[xm], d[s][6]);                      \
            d[s][7] = fma(cd, (double)Y2[xc], d[s][7]);                      \
            d[s][8] = fma(cd, (double)Y2[xp], d[s][8]);                      \
            double ov = (double)Y1[xc];                                      \
            qs[s] = fma(ov, ov, qs[s]);                                      \
        }                                                                    \
    }

    for (int n = 0; n < 64; n += 4) {
        *(f32x4*)d00 = a0; *(f32x4*)d01 = a1;   // chans n, n+1 -> buf0
        __syncthreads();
        if (n + 4 < 64) {
            a0 = *(const f32x4*)(x + gbase + (size_t)(n + 4) * P);
            a1 = *(const f32x4*)(x + gbase + (size_t)(n + 5) * P);
        }
        COMPUTE(0, 0) COMPUTE(0, 1)             // chans n, n+1
        *(f32x4*)d10 = b0; *(f32x4*)d11 = b1;   // chans n+2, n+3 -> buf1
        __syncthreads();
        if (n + 6 < 64) {
            b0 = *(const f32x4*)(x + gbase + (size_t)(n + 6) * P);
            b1 = *(const f32x4*)(x + gbase + (size_t)(n + 7) * P);
        }
        COMPUTE(1, 0) COMPUTE(1, 1)             // chans n+2, n+3
    }
    #undef COMPUTE

    const int p = strip * 256 + t;
    double* db = (double*)(out + (size_t)(b * 3) * CP);
    #pragma unroll
    for (int s = 0; s < 2; ++s) {
        #pragma unroll
        for (int k = 0; k < 9; ++k)
            db[DOT_D_OFF + (size_t)((chunk * 2 + s) * 9 + k) * 4096 + p] = d[s][k];
        db[SSQ_D_OFF + (size_t)(chunk * 2 + s) * 4096 + p] = qs[s];
    }
}

// ---------------------------------------------------------------------------
// Kernel: final argmin over 9 neighbors, with inv-norm fused (round 11).
// Fixed chunk-order fp64 sums; duplicates bit-identical; strict < tie-break.
// ---------------------------------------------------------------------------
__global__ __launch_bounds__(256) void k_sel(float* __restrict__ out) {
    int gid  = blockIdx.x * 256 + threadIdx.x;
    int side = gid >> 15;
    int j    = gid & (J - 1);
    int b = j >> 12, p = j & (P - 1);
    int y = p >> 6, xc = p & 63;

    int nidx[9];
    #pragma unroll
    for (int k = 0; k < 9; ++k) {
        int dy = k / 3 - 1, dx = k % 3 - 1;     // y_off=repeat, x_off=tile
        int yy = min(max(y + dy, 0), Hh - 1);
        int xx = min(max(xc + dx, 0), Ww - 1);
        nidx[k] = yy * Ww + xx;
    }

    const double* db = (const double*)(out + (size_t)(b * 3) * CP) + DOT_D_OFF;
    const double* sb = (const double*)(out + (size_t)(b * 3) * CP) + SSQ_D_OFF;

    double best = 0.0; int bi = 0; float sivbest = 0.0f;
    #pragma unroll
    for (int k = 0; k < 9; ++k) {
        int nq = nidx[k];
        double ssum = ((sb[(0 * 2 + side) * 4096 + nq]
                      + sb[(1 * 2 + side) * 4096 + nq])
                      + sb[(2 * 2 + side) * 4096 + nq])
                      + sb[(3 * 2 + side) * 4096 + nq];
        float ivf = 1.0f / fmaxf((float)sqrt(ssum), 1e-12f);
        double sk = ((db[(size_t)((0 * 2 + side) * 9 + k) * 4096 + p]
                    + db[(size_t)((1 * 2 + side) * 9 + k) * 4096 + p])
                    + db[(size_t)((2 * 2 + side) * 9 + k) * 4096 + p])
                    + db[(size_t)((3 * 2 + side) * 9 + k) * 4096 + p];
        double s = sk * (double)ivf;
        if (k == 0 || s < best) { best = s; bi = k; sivbest = ivf; }
    }
    int*   selb = (int*)(out + (size_t)(b * 3) * CP + SEL_F_OFF);
    float* sivb = out + (size_t)(b * 3) * CP + SIV_F_OFF;
    selb[side * 4096 + p] = nidx[bi];
    sivb[side * 4096 + p] = sivbest;
}

// ---------------------------------------------------------------------------
// Kernel: bf16 MFMA GEMM, software-pipelined, with FUSED BN-stats epilogue
// (round 13: acc registers already hold every conv output; per-wave fp32
// g-sum + l16 butterfly -> LDS -> one fp64 atomicAdd per channel per block
// into BNS slab, now DISJOINT from Wb. Saves k_bn's 100MB stats read.
// Stats precision: fp32 over 64 cols then fp64 accumulate => mean/var rel
// err ~1e-6, invisible vs 0.108 threshold / bf16-GEMM rounding.)
// ---------------------------------------------------------------------------
__global__ __launch_bounds__(512) void k_gemm(const float* __restrict__ x,
                                              const unsigned short* __restrict__ Wb,
                                              float* __restrict__ out) {
    __shared__ unsigned short As[2][4][256][8];   // 32 KB, k-octet blocked
    __shared__ unsigned short Bs[2][4][128][8];   // 16 KB
    __shared__ int   sel_s[2][128];
    __shared__ float siv_s[2][128];
    __shared__ float sw_s[8][64], sw_q[8][64];    // per-wave BN partials 4 KB

    const int t  = threadIdx.x;
    const int j0 = blockIdx.x * 128;
    const int b  = j0 >> 12, p0 = j0 & (P - 1);   // 128 | 4096 -> b uniform

    if (t < 256) {
        int side = t >> 7, jj = t & 127;
        const int*   selb = (const int*)(out + (size_t)(b * 3) * CP + SEL_F_OFF);
        const float* sivb = out + (size_t)(b * 3) * CP + SIV_F_OFF;
        sel_s[side][jj] = selb[side * 4096 + p0 + jj];
        siv_s[side][jj] = sivb[side * 4096 + p0 + jj];
    }
    __syncthreads();

    const int lane = t & 63, w = t >> 6;
    const int q = lane >> 4, l16 = lane & 15;
    const int m0w = (w & 3) * 64;      // 4 m-quadrants of 256
    const int n0w = (w >> 2) * 64;     // 2 n-halves of 128

    const int jj = t & 127, kq = (t >> 7) & 3;   // B staging role
    const int ma = t & 255, kh = t >> 8;         // A staging role
    const int k0 = kq * 8;

    // hoisted gather bases + scales
    const float* pp = x + (size_t)(b * 3 + 0) * CP + sel_s[0][jj];
    const float* np = x + (size_t)(b * 3 + 1) * CP + sel_s[1][jj];
    const float* cp = x + (size_t)(b * 3 + 2) * CP + p0 + jj;
    const float  sp = siv_s[0][jj], sn = siv_s[1][jj];
    const unsigned short* wbase = Wb + (size_t)ma * CT + kh * 16;

    f32x4 acc[4][4];
    #pragma unroll
    for (int f = 0; f < 4; ++f)
        #pragma unroll
        for (int g = 0; g < 4; ++g)
            acc[f][g] = (f32x4){0.f, 0.f, 0.f, 0.f};

    short8 wa0, wa1;
    float fb[8];
    float scale;

    #define LOAD_STEP(KK)                                                    \
    {                                                                        \
        const unsigned short* wsrc = wbase + (KK);                           \
        wa0 = *(const short8*)wsrc;                                          \
        wa1 = *(const short8*)(wsrc + 8);                                    \
        const float* src;                                                    \
        if ((KK) < 256)      { src = pp + (size_t)((KK) + k0) * P;       scale = sp;   } \
        else if ((KK) < 512) { src = np + (size_t)((KK) - 256 + k0) * P; scale = sn;   } \
        else                 { src = cp + (size_t)((KK) - 512 + k0) * P; scale = 1.0f; } \
        _Pragma("unroll")                                                    \
        for (int u = 0; u < 8; ++u) fb[u] = src[(size_t)u * P];              \
    }

    #define WRITE_STEP(BUF)                                                  \
    {                                                                        \
        *(short8*)&As[BUF][kh * 2    ][ma][0] = wa0;                         \
        *(short8*)&As[BUF][kh * 2 + 1][ma][0] = wa1;                         \
        uint4 pk = make_uint4(pack2(fb[0] * scale, fb[1] * scale),           \
                              pack2(fb[2] * scale, fb[3] * scale),           \
                              pack2(fb[4] * scale, fb[5] * scale),           \
                              pack2(fb[6] * scale, fb[7] * scale));          \
        *(uint4*)&Bs[BUF][kq][jj][0] = pk;                                   \
    }

    LOAD_STEP(0)
    WRITE_STEP(0)
    __syncthreads();

    for (int i = 0; i < 24; ++i) {
        if (i + 1 < 24) LOAD_STEP((i + 1) * 32)       // in flight during MFMA
        const int cur = i & 1;
        short8 af[4], bfr[4];
        #pragma unroll
        for (int f = 0; f < 4; ++f)
            af[f] = *(const short8*)&As[cur][q][m0w + f * 16 + l16][0];
        #pragma unroll
        for (int g = 0; g < 4; ++g)
            bfr[g] = *(const short8*)&Bs[cur][q][n0w + g * 16 + l16][0];
        #pragma unroll
        for (int f = 0; f < 4; ++f)
            #pragma unroll
            for (int g = 0; g < 4; ++g)
                acc[f][g] = __builtin_amdgcn_mfma_f32_16x16x32_bf16(
                    af[f], bfr[g], acc[f][g], 0, 0, 0);
        if (i + 1 < 24) WRITE_STEP((i + 1) & 1)
        __syncthreads();
    }
    #undef LOAD_STEP
    #undef WRITE_STEP

    // epilogue 1: C-store. D[row=q*4+r][col=l16] per 16x16 frag
    float* outb = out + (size_t)(b * 3 + 2) * CP;
    #pragma unroll
    for (int f = 0; f < 4; ++f)
        #pragma unroll
        for (int g = 0; g < 4; ++g)
            #pragma unroll
            for (int r = 0; r < 4; ++r) {
                int ch  = m0w + f * 16 + q * 4 + r;
                int col = p0 + n0w + g * 16 + l16;
                outb[(size_t)ch * P + col] = acc[f][g][r];
            }

    // epilogue 2: BN stats. Per (f,r): fp32 sum/sumsq over 4 g-frags,
    // butterfly over l16 lanes (masks 1..8 stay within the 16-lane group),
    // lane l16==0 stashes per-wave partial; then 256 threads combine the
    // two n-half waves and atomicAdd (fp64) into the global slab.
    #pragma unroll
    for (int f = 0; f < 4; ++f)
        #pragma unroll
        for (int r = 0; r < 4; ++r) {
            float s  = acc[f][0][r] + acc[f][1][r] + acc[f][2][r] + acc[f][3][r];
            float qq = acc[f][0][r] * acc[f][0][r] + acc[f][1][r] * acc[f][1][r]
                     + acc[f][2][r] * acc[f][2][r] + acc[f][3][r] * acc[f][3][r];
            #pragma unroll
            for (int m = 1; m <= 8; m <<= 1) {
                s  += __shfl_xor(s, m);
                qq += __shfl_xor(qq, m);
            }
            if (l16 == 0) {
                sw_s[w][f * 16 + q * 4 + r] = s;
                sw_q[w][f * 16 + q * 4 + r] = qq;
            }
        }
    __syncthreads();
    if (t < 256) {
        int quad = t >> 6, lch = t & 63;        // ch = t
        double s  = (double)sw_s[quad][lch] + (double)sw_s[4 + quad][lch];
        double qq = (double)sw_q[quad][lch] + (double)sw_q[4 + quad][lch];
        double* bns = (double*)out + BNS_D_OFF;
        atomicAdd(&bns[t], s);
        atomicAdd(&bns[256 + t], qq);
    }
}

// ---------------------------------------------------------------------------
// Kernel: BN normalize + ReLU, SINGLE PASS (stats precomputed by gemm
// epilogue into BNS slab; saves the 100MB stats read)
// ---------------------------------------------------------------------------
__global__ __launch_bounds__(256) void k_bn(float* __restrict__ out,
                                            const float* __restrict__ gamma,
                                            const float* __restrict__ beta) {
    const int o = blockIdx.x, t = threadIdx.x;
    const double* bns = (const double*)out + BNS_D_OFF;
    double mean = bns[o] * (1.0 / (double)J);
    double var  = bns[256 + o] * (1.0 / (double)J) - mean * mean;
    double inv  = 1.0 / sqrt(var + 1e-5);
    double scd  = (double)gamma[o] * inv;
    const float sc = (float)scd;
    const float sh = (float)((double)beta[o] - mean * scd);

    for (int b = 0; b < B; ++b) {
        float4* base =
            (float4*)(out + (size_t)(b * 3 + 2) * CP + (size_t)o * P);
        #pragma unroll
        for (int i = 0; i < 4; ++i) {
            float4 v = base[i * 256 + t];
            v.x = fmaxf(fmaf(v.x, sc, sh), 0.f);
            v.y = fmaxf(fmaf(v.y, sc, sh), 0.f);
            v.z = fmaxf(fmaf(v.z, sc, sh), 0.f);
            v.w = fmaxf(fmaf(v.w, sc, sh), 0.f);
            base[i * 256 + t] = v;
        }
    }
}

// ---------------------------------------------------------------------------
// Kernel: copy prev/next slices to output slots 0/1 (runs LAST: overwrites
// the scratch region used by earlier kernels)
// ---------------------------------------------------------------------------
__global__ __launch_bounds__(256) void k_copy(const float4* __restrict__ x4,
                                              float4* __restrict__ o4) {
    int tid = blockIdx.x * blockDim.x + threadIdx.x;
    const int per_b = 2 * CP / 4;
    const int bstr  = 3 * CP / 4;
    if (tid < B * per_b) {
        int b = tid / per_b;
        int r = tid - b * per_b;
        o4[b * bstr + r] = x4[b * bstr + r];
    }
}

// ---------------------------------------------------------------------------
extern "C" void kernel_launch(void* const* d_in, const int* in_sizes, int n_in,
                              void* d_out, int out_size, void* d_ws, size_t ws_size,
                              hipStream_t stream) {
    const float* x     = (const float*)d_in[0];
    const float* wconv = (const float*)d_in[1];
    const float* gamma = (const float*)d_in[2];
    const float* beta  = (const float*)d_in[3];
    float* out = (float*)d_out;
    (void)d_ws; (void)ws_size;   // deliberately unused

    unsigned short* Wbuf = (unsigned short*)(out + WB_F_OFF);

    k_wcvt<<<CT * C / 256, 256, 0, stream>>>(wconv, Wbuf, out);

    // fused dots+sumsq: (8 batches x 16 strips) x 4 channel chunks
    k_dots<<<dim3(128, 4), 256, 0, stream>>>(x, out);

    // argmin with fused inv-norm
    k_sel<<<2 * J / 256, 256, 0, stream>>>(out);

    // GEMM with fused BN-stats accumulation
    k_gemm<<<J / 128, 512, 0, stream>>>(x, Wbuf, out);

    // single-pass normalize + ReLU
    k_bn<<<C, 256, 0, stream>>>(out, gamma, beta);

    k_copy<<<(B * 2 * CP / 4 + 255) / 256, 256, 0, stream>>>(
        (const float4*)x, (float4*)out);
}

// Round 15
// 253.572 us; speedup vs baseline: 1.5726x; 1.0147x over previous
//
#include <hip/hip_runtime.h>

// Problem constants
constexpr int B  = 8;
constexpr int C  = 256;
constexpr int Hh = 64;
constexpr int Ww = 64;
constexpr int P  = Hh * Ww;        // 4096 pixels
constexpr int CP = C * P;          // elements per (b,t) slice
constexpr int CT = 3 * C;          // 768 concat channels
constexpr int J  = B * P;          // 32768 columns

// Per-batch scratch inside out slot-0 of batch b (4-chunk layout).
// DOT/SSQ/BNS offsets in DOUBLES from slot-0 base; WB in floats.
// k_copy overwrites slots 0/1 LAST; gemm writes slot 2 only -> no overlap.
// Batch-0 slot-0 additionally holds WB + BNS (disjoint from per-batch regions):
//   DOT  floats       0..589824   (294912 doubles)
//   SSQ  floats  589824..655360   (32768 doubles at d-off 294912)
//   WB   floats  679936..778240   (196608 u16 = 98304 floats)
//   BNS  floats  778240..779264   (512 doubles at d-off 389120)
constexpr int DOT_D_OFF = 0;        // double[4][2][9][4096] (chunk,side,k,p)
constexpr int SSQ_D_OFF = 294912;   // double[4][2][4096]    (chunk,side,p)
constexpr int WB_F_OFF  = 679936;   // bf16 weights (batch-0 only)
constexpr int BNS_D_OFF = 389120;   // double[512]: sums[256], sumsq[256]

typedef __attribute__((ext_vector_type(8))) short short8;
typedef __attribute__((ext_vector_type(4))) float f32x4;

__device__ inline unsigned short bf16_rne(float f) {
    unsigned u = __float_as_uint(f);
    return (unsigned short)((u + 0x7fffu + ((u >> 16) & 1u)) >> 16);
}
__device__ inline unsigned pack2(float a, float b) {
    return (unsigned)bf16_rne(a) | ((unsigned)bf16_rne(b) << 16);
}

// ---------------------------------------------------------------------------
// Kernel: fused neighbor-dots + sumsq (proven rounds 8/11), now ALSO
// absorbing weight-cvt + BNS zeroing (round 14: each of 512 blocks converts
// 384 weight elems; block lid==0 zeroes BNS slab — rides under dots' BW,
// saves the k_wcvt launch).
// Block = 4-row strip (256 px) x 64-ch chunk; TWO channels staged per LDS
// phase (2 float4 loads/thread/phase, 4 in flight). Per-thread accumulation
// ascending-channel => partials bit-identical to round 8. Partials (18 dots
// + 2 sumsq fp64) -> per-batch scratch; fixed chunk order downstream =>
// strict-< tie-break preserved.
// ---------------------------------------------------------------------------
__global__ __launch_bounds__(256) void k_dots(const float* __restrict__ x,
                                              const float* __restrict__ Wg,
                                              float* __restrict__ out) {
    __shared__ float ys[2][2][2][6][64];  // [buf][ch][side][row][x] 12 KB
    __shared__ float cs[2][2][256];       // [buf][ch][px]            4 KB
    const int t     = threadIdx.x;
    const int b     = blockIdx.x >> 4;
    const int strip = blockIdx.x & 15;
    const int chunk = blockIdx.y;       // 0..3 -> channels [64*chunk, +64)

    // --- absorbed k_wcvt: 512 blocks x 384 elems = 196608, exact ---
    {
        int lid  = blockIdx.y * 128 + blockIdx.x;    // 0..511
        int base = lid * 384;
        unsigned short* Wb = (unsigned short*)(out + WB_F_OFF);
        Wb[base + t] = bf16_rne(Wg[base + t]);
        if (t < 128) Wb[base + 256 + t] = bf16_rne(Wg[base + 256 + t]);
        if (lid == 0) {                              // zero BNS slab
            double* bns = (double*)out + BNS_D_OFF;
            bns[t] = 0.0; bns[256 + t] = 0.0;
        }
    }

    const int y0 = strip * 4;
    const int ry = t >> 6;              // own row in strip (0..3)
    const int xc = t & 63;
    const int xm = max(xc - 1, 0), xp = min(xc + 1, 63);
    const int c0 = chunk * 64;

    // one float4 staging slot per thread per channel:
    // 64 cur + 96 prev + 96 next = 256 slots
    size_t gbase;
    float *d00, *d01, *d10, *d11;       // [buf][ch-in-pair] destinations
    float* ysf = &ys[0][0][0][0][0];    // strides: buf 1536, ch 768
    float* csf = &cs[0][0][0];          // strides: buf 512,  ch 256
    if (t < 64) {
        gbase = (size_t)(b * 3 + 2) * CP + (size_t)c0 * P + strip * 256 + t * 4;
        int l0 = t * 4;
        d00 = csf + l0;        d01 = csf + 256 + l0;
        d10 = csf + 512 + l0;  d11 = csf + 768 + l0;
    } else {
        int i   = t - 64;               // 0..191
        int sid = i >= 96;              // 0=prev, 1=next
        int r   = (i - sid * 96) >> 4;  // staged row 0..5
        int x4  = i & 15;
        int yl  = min(max(y0 - 1 + r, 0), Hh - 1);
        gbase = (size_t)(b * 3 + sid) * CP + (size_t)c0 * P + yl * 64 + x4 * 4;
        int l0 = (sid * 6 + r) * 64 + x4 * 4;      // 0..767
        d00 = ysf + l0;         d01 = ysf + 768 + l0;
        d10 = ysf + 1536 + l0;  d11 = ysf + 1536 + 768 + l0;
    }

    double d[2][9] = {{0,0,0,0,0,0,0,0,0},{0,0,0,0,0,0,0,0,0}};
    double qs[2] = {0.0, 0.0};

    f32x4 a0 = *(const f32x4*)(x + gbase);                      // chan 0
    f32x4 a1 = *(const f32x4*)(x + gbase + (size_t)P);          // chan 1
    f32x4 b0 = *(const f32x4*)(x + gbase + (size_t)2 * P);      // chan 2
    f32x4 b1 = *(const f32x4*)(x + gbase + (size_t)3 * P);      // chan 3

    #define COMPUTE(BUF, CH)                                                 \
    {                                                                        \
        double cd = (double)cs[BUF][CH][t];                                  \
        _Pragma("unroll")                                                    \
        for (int s = 0; s < 2; ++s) {                                        \
            const float* Y0 = &ys[BUF][CH][s][ry][0];   /* own y - 1 */      \
            const float* Y1 = Y0 + 64;                  /* own y     */      \
            const float* Y2 = Y1 + 64;                  /* own y + 1 */      \
            d[s][0] = fma(cd, (double)Y0[xm], d[s][0]);                      \
            d[s][1] = fma(cd, (double)Y0[xc], d[s][1]);                      \
            d[s][2] = fma(cd, (double)Y0[xp], d[s][2]);                      \
            d[s][3] = fma(cd, (double)Y1[xm], d[s][3]);                      \
            d[s][4] = fma(cd, (double)Y1[xc], d[s][4]);                      \
            d[s][5] = fma(cd, (double)Y1[xp], d[s][5]);                      \
            d[s][6] = fma(cd, (double)Y2[xm], d[s][6]);                      \
            d[s][7] = fma(cd, (double)Y2[xc], d[s][7]);                      \
            d[s][8] = fma(cd, (double)Y2[xp], d[s][8]);                      \
            double ov = (double)Y1[xc];                                      \
            qs[s] = fma(ov, ov, qs[s]);                                      \
        }                                                                    \
    }

    for (int n = 0; n < 64; n += 4) {
        *(f32x4*)d00 = a0; *(f32x4*)d01 = a1;   // chans n, n+1 -> buf0
        __syncthreads();
        if (n + 4 < 64) {
            a0 = *(const f32x4*)(x + gbase + (size_t)(n + 4) * P);
            a1 = *(const f32x4*)(x + gbase + (size_t)(n + 5) * P);
        }
        COMPUTE(0, 0) COMPUTE(0, 1)             // chans n, n+1
        *(f32x4*)d10 = b0; *(f32x4*)d11 = b1;   // chans n+2, n+3 -> buf1
        __syncthreads();
        if (n + 6 < 64) {
            b0 = *(const f32x4*)(x + gbase + (size_t)(n + 6) * P);
            b1 = *(const f32x4*)(x + gbase + (size_t)(n + 7) * P);
        }
        COMPUTE(1, 0) COMPUTE(1, 1)             // chans n+2, n+3
    }
    #undef COMPUTE

    const int p = strip * 256 + t;
    double* db = (double*)(out + (size_t)(b * 3) * CP);
    #pragma unroll
    for (int s = 0; s < 2; ++s) {
        #pragma unroll
        for (int k = 0; k < 9; ++k)
            db[DOT_D_OFF + (size_t)((chunk * 2 + s) * 9 + k) * 4096 + p] = d[s][k];
        db[SSQ_D_OFF + (size_t)(chunk * 2 + s) * 4096 + p] = qs[s];
    }
}

// ---------------------------------------------------------------------------
// Kernel: bf16 MFMA GEMM, software-pipelined, with FUSED argmin (round 14:
// absorbs k_sel — t<256 compute sel/siv for the block's 128 px x 2 sides
// directly from DOT/SSQ partials, exact same expressions/order => selections
// bit-identical; straight to LDS, no global round-trip) and FUSED BN-stats
// epilogue (round 13).
// ---------------------------------------------------------------------------
__global__ __launch_bounds__(512) void k_gemm(const float* __restrict__ x,
                                              float* __restrict__ out) {
    __shared__ unsigned short As[2][4][256][8];   // 32 KB, k-octet blocked
    __shared__ unsigned short Bs[2][4][128][8];   // 16 KB
    __shared__ int   sel_s[2][128];
    __shared__ float siv_s[2][128];
    __shared__ float sw_s[8][64], sw_q[8][64];    // per-wave BN partials 4 KB

    const int t  = threadIdx.x;
    const int j0 = blockIdx.x * 128;
    const int b  = j0 >> 12, p0 = j0 & (P - 1);   // 128 | 4096 -> b uniform
    const unsigned short* Wb = (const unsigned short*)(out + WB_F_OFF);

    // --- absorbed k_sel: argmin + inv-norm for this block's pixels ---
    if (t < 256) {
        int side = t >> 7, jj = t & 127;
        int p = p0 + jj;
        int y = p >> 6, xc = p & 63;
        int nidx[9];
        #pragma unroll
        for (int k = 0; k < 9; ++k) {
            int dy = k / 3 - 1, dx = k % 3 - 1;     // y_off=repeat, x_off=tile
            int yy = min(max(y + dy, 0), Hh - 1);
            int xx = min(max(xc + dx, 0), Ww - 1);
            nidx[k] = yy * Ww + xx;
        }
        const double* db = (const double*)(out + (size_t)(b * 3) * CP) + DOT_D_OFF;
        const double* sb = (const double*)(out + (size_t)(b * 3) * CP) + SSQ_D_OFF;
        double best = 0.0; int bi = 0; float sivbest = 0.0f;
        #pragma unroll
        for (int k = 0; k < 9; ++k) {
            int nq = nidx[k];
            double ssum = ((sb[(0 * 2 + side) * 4096 + nq]
                          + sb[(1 * 2 + side) * 4096 + nq])
                          + sb[(2 * 2 + side) * 4096 + nq])
                          + sb[(3 * 2 + side) * 4096 + nq];
            float ivf = 1.0f / fmaxf((float)sqrt(ssum), 1e-12f);
            double sk = ((db[(size_t)((0 * 2 + side) * 9 + k) * 4096 + p]
                        + db[(size_t)((1 * 2 + side) * 9 + k) * 4096 + p])
                        + db[(size_t)((2 * 2 + side) * 9 + k) * 4096 + p])
                        + db[(size_t)((3 * 2 + side) * 9 + k) * 4096 + p];
            double s = sk * (double)ivf;
            if (k == 0 || s < best) { best = s; bi = k; sivbest = ivf; }
        }
        sel_s[side][jj] = nidx[bi];
        siv_s[side][jj] = sivbest;
    }
    __syncthreads();

    const int lane = t & 63, w = t >> 6;
    const int q = lane >> 4, l16 = lane & 15;
    const int m0w = (w & 3) * 64;      // 4 m-quadrants of 256
    const int n0w = (w >> 2) * 64;     // 2 n-halves of 128

    const int jj = t & 127, kq = (t >> 7) & 3;   // B staging role
    const int ma = t & 255, kh = t >> 8;         // A staging role
    const int k0 = kq * 8;

    // hoisted gather bases + scales
    const float* pp = x + (size_t)(b * 3 + 0) * CP + sel_s[0][jj];
    const float* np = x + (size_t)(b * 3 + 1) * CP + sel_s[1][jj];
    const float* cp = x + (size_t)(b * 3 + 2) * CP + p0 + jj;
    const float  sp = siv_s[0][jj], sn = siv_s[1][jj];
    const unsigned short* wbase = Wb + (size_t)ma * CT + kh * 16;

    f32x4 acc[4][4];
    #pragma unroll
    for (int f = 0; f < 4; ++f)
        #pragma unroll
        for (int g = 0; g < 4; ++g)
            acc[f][g] = (f32x4){0.f, 0.f, 0.f, 0.f};

    short8 wa0, wa1;
    float fb[8];
    float scale;

    #define LOAD_STEP(KK)                                                    \
    {                                                                        \
        const unsigned short* wsrc = wbase + (KK);                           \
        wa0 = *(const short8*)wsrc;                                          \
        wa1 = *(const short8*)(wsrc + 8);                                    \
        const float* src;                                                    \
        if ((KK) < 256)      { src = pp + (size_t)((KK) + k0) * P;       scale = sp;   } \
        else if ((KK) < 512) { src = np + (size_t)((KK) - 256 + k0) * P; scale = sn;   } \
        else                 { src = cp + (size_t)((KK) - 512 + k0) * P; scale = 1.0f; } \
        _Pragma("unroll")                                                    \
        for (int u = 0; u < 8; ++u) fb[u] = src[(size_t)u * P];              \
    }

    #define WRITE_STEP(BUF)                                                  \
    {                                                                        \
        *(short8*)&As[BUF][kh * 2    ][ma][0] = wa0;                         \
        *(short8*)&As[BUF][kh * 2 + 1][ma][0] = wa1;                         \
        uint4 pk = make_uint4(pack2(fb[0] * scale, fb[1] * scale),           \
                              pack2(fb[2] * scale, fb[3] * scale),           \
                              pack2(fb[4] * scale, fb[5] * scale),           \
                              pack2(fb[6] * scale, fb[7] * scale));          \
        *(uint4*)&Bs[BUF][kq][jj][0] = pk;                                   \
    }

    LOAD_STEP(0)
    WRITE_STEP(0)
    __syncthreads();

    for (int i = 0; i < 24; ++i) {
        if (i + 1 < 24) LOAD_STEP((i + 1) * 32)       // in flight during MFMA
        const int cur = i & 1;
        short8 af[4], bfr[4];
        #pragma unroll
        for (int f = 0; f < 4; ++f)
            af[f] = *(const short8*)&As[cur][q][m0w + f * 16 + l16][0];
        #pragma unroll
        for (int g = 0; g < 4; ++g)
            bfr[g] = *(const short8*)&Bs[cur][q][n0w + g * 16 + l16][0];
        #pragma unroll
        for (int f = 0; f < 4; ++f)
            #pragma unroll
            for (int g = 0; g < 4; ++g)
                acc[f][g] = __builtin_amdgcn_mfma_f32_16x16x32_bf16(
                    af[f], bfr[g], acc[f][g], 0, 0, 0);
        if (i + 1 < 24) WRITE_STEP((i + 1) & 1)
        __syncthreads();
    }
    #undef LOAD_STEP
    #undef WRITE_STEP

    // epilogue 1: C-store. D[row=q*4+r][col=l16] per 16x16 frag
    float* outb = out + (size_t)(b * 3 + 2) * CP;
    #pragma unroll
    for (int f = 0; f < 4; ++f)
        #pragma unroll
        for (int g = 0; g < 4; ++g)
            #pragma unroll
            for (int r = 0; r < 4; ++r) {
                int ch  = m0w + f * 16 + q * 4 + r;
                int col = p0 + n0w + g * 16 + l16;
                outb[(size_t)ch * P + col] = acc[f][g][r];
            }

    // epilogue 2: BN stats. Per (f,r): fp32 sum/sumsq over 4 g-frags,
    // butterfly over l16 lanes, lane l16==0 stashes per-wave partial;
    // 256 threads combine n-half waves and fp64-atomicAdd into BNS slab.
    #pragma unroll
    for (int f = 0; f < 4; ++f)
        #pragma unroll
        for (int r = 0; r < 4; ++r) {
            float s  = acc[f][0][r] + acc[f][1][r] + acc[f][2][r] + acc[f][3][r];
            float qq = acc[f][0][r] * acc[f][0][r] + acc[f][1][r] * acc[f][1][r]
                     + acc[f][2][r] * acc[f][2][r] + acc[f][3][r] * acc[f][3][r];
            #pragma unroll
            for (int m = 1; m <= 8; m <<= 1) {
                s  += __shfl_xor(s, m);
                qq += __shfl_xor(qq, m);
            }
            if (l16 == 0) {
                sw_s[w][f * 16 + q * 4 + r] = s;
                sw_q[w][f * 16 + q * 4 + r] = qq;
            }
        }
    __syncthreads();
    if (t < 256) {
        int quad = t >> 6, lch = t & 63;        // ch = t
        double s  = (double)sw_s[quad][lch] + (double)sw_s[4 + quad][lch];
        double qq = (double)sw_q[quad][lch] + (double)sw_q[4 + quad][lch];
        double* bns = (double*)out + BNS_D_OFF;
        atomicAdd(&bns[t], s);
        atomicAdd(&bns[256 + t], qq);
    }
}

// ---------------------------------------------------------------------------
// Kernel: BN normalize + ReLU, single pass (stats from gemm epilogue).
// NOT merged with k_copy: copy overwrites batch-0 slot-0 (where BNS lives)
// and intra-kernel block order is undefined -> would race on BNS.
// ---------------------------------------------------------------------------
__global__ __launch_bounds__(256) void k_bn(float* __restrict__ out,
                                            const float* __restrict__ gamma,
                                            const float* __restrict__ beta) {
    const int o = blockIdx.x, t = threadIdx.x;
    const double* bns = (const double*)out + BNS_D_OFF;
    double mean = bns[o] * (1.0 / (double)J);
    double var  = bns[256 + o] * (1.0 / (double)J) - mean * mean;
    double inv  = 1.0 / sqrt(var + 1e-5);
    double scd  = (double)gamma[o] * inv;
    const float sc = (float)scd;
    const float sh = (float)((double)beta[o] - mean * scd);

    for (int b = 0; b < B; ++b) {
        float4* base =
            (float4*)(out + (size_t)(b * 3 + 2) * CP + (size_t)o * P);
        #pragma unroll
        for (int i = 0; i < 4; ++i) {
            float4 v = base[i * 256 + t];
            v.x = fmaxf(fmaf(v.x, sc, sh), 0.f);
            v.y = fmaxf(fmaf(v.y, sc, sh), 0.f);
            v.z = fmaxf(fmaf(v.z, sc, sh), 0.f);
            v.w = fmaxf(fmaf(v.w, sc, sh), 0.f);
            base[i * 256 + t] = v;
        }
    }
}

// ---------------------------------------------------------------------------
// Kernel: copy prev/next slices to output slots 0/1 (runs LAST: overwrites
// the scratch region used by earlier kernels)
// ---------------------------------------------------------------------------
__global__ __launch_bounds__(256) void k_copy(const float4* __restrict__ x4,
                                              float4* __restrict__ o4) {
    int tid = blockIdx.x * blockDim.x + threadIdx.x;
    const int per_b = 2 * CP / 4;
    const int bstr  = 3 * CP / 4;
    if (tid < B * per_b) {
        int b = tid / per_b;
        int r = tid - b * per_b;
        o4[b * bstr + r] = x4[b * bstr + r];
    }
}

// ---------------------------------------------------------------------------
extern "C" void kernel_launch(void* const* d_in, const int* in_sizes, int n_in,
                              void* d_out, int out_size, void* d_ws, size_t ws_size,
                              hipStream_t stream) {
    const float* x     = (const float*)d_in[0];
    const float* wconv = (const float*)d_in[1];
    const float* gamma = (const float*)d_in[2];
    const float* beta  = (const float*)d_in[3];
    float* out = (float*)d_out;
    (void)d_ws; (void)ws_size;   // deliberately unused

    // dots + weight-cvt + BNS-zero: (8 batches x 16 strips) x 4 chunks
    k_dots<<<dim3(128, 4), 256, 0, stream>>>(x, wconv, out);

    // GEMM with fused argmin prologue + BN-stats epilogue
    k_gemm<<<J / 128, 512, 0, stream>>>(x, out);

    // single-pass normalize + ReLU
    k_bn<<<C, 256, 0, stream>>>(out, gamma, beta);

    k_copy<<<(B * 2 * CP / 4 + 255) / 256, 256, 0, stream>>>(
        (const float4*)x, (float4*)out);
}